// Round 1
// baseline (1824.673 us; speedup 1.0000x reference)
//
#include <hip/hip_runtime.h>

// ---------------------------------------------------------------------------
// Swin-V2 window attention, MI355X (gfx950).
// B=1024 windows, N=64 tokens, C=512, NH=8 heads, HD=64.
// Structure:
//   K0 wconv : qkv_w / proj_w f32 -> bf16 (ws)
//   K1 cpb   : continuous rel-pos-bias MLP -> bias table [8][64][64] f32 (ws)
//   K2 fused : per-window  QKV(MFMA bf16) + cosine-attn (fp32 softmax,
//              QK^T & PV via MFMA bf16) -> attn_out bf16 (ws)
//   K3 proj  : [65536x512] @ [512x512]^T + bias -> out f32
// ---------------------------------------------------------------------------

typedef __bf16 bf16;
typedef bf16  bf16x8 __attribute__((ext_vector_type(8)));
typedef float f32x4  __attribute__((ext_vector_type(4)));

#define MFMA16(a, b, c) __builtin_amdgcn_mfma_f32_16x16x32_bf16((a), (b), (c), 0, 0, 0)

__device__ __forceinline__ unsigned short f2bf_bits(float f) {
  return __builtin_bit_cast(unsigned short, (bf16)f);
}

// ws layout (bytes)
#define OFF_BIAS   0          // 8*64*64*4   = 131072
#define OFF_QKVW   131072     // 1536*512*2  = 1572864
#define OFF_PROJW  1703936    // 512*512*2   = 524288
#define OFF_ATTN   2228224    // 65536*512*2 = 67108864  (total ~66.2 MB)

// ---------------------------------------------------------------------------
// K0: weight conversion f32 -> bf16. 262144 float4 total (qkv: 196608, proj: 65536)
// ---------------------------------------------------------------------------
__global__ void wconv_kernel(const float* __restrict__ qkvw,
                             const float* __restrict__ projw,
                             bf16* __restrict__ qkvw_bf,
                             bf16* __restrict__ projw_bf) {
  int i = blockIdx.x * 256 + threadIdx.x;
#pragma unroll
  for (int it = 0; it < 4; ++it) {
    int idx = i + it * 65536;
    const float4* src;
    bf16* dst;
    if (idx < 196608) {
      src = ((const float4*)qkvw) + idx;
      dst = qkvw_bf + idx * 4;
    } else {
      int j = idx - 196608;
      src = ((const float4*)projw) + j;
      dst = projw_bf + j * 4;
    }
    float4 v = *src;
    ushort4 o;
    o.x = f2bf_bits(v.x); o.y = f2bf_bits(v.y);
    o.z = f2bf_bits(v.z); o.w = f2bf_bits(v.w);
    *(ushort4*)dst = o;
  }
}

// ---------------------------------------------------------------------------
// K1: CPB bias table. rel coords / rel idx recomputed in-kernel (module consts).
// biasmat[h][qi][kj] = 16*sigmoid( relu(coords @ w1^T + b1) @ w2^T )[relidx][h]
// ---------------------------------------------------------------------------
__global__ void cpb_kernel(const float* __restrict__ w1, const float* __restrict__ b1,
                           const float* __restrict__ w2, float* __restrict__ biasmat) {
  __shared__ float cpb_s[225][8];
  int t = threadIdx.x;
  if (t < 225) {
    int a = t / 15, b = t % 15;
    float rh = (float)(a - 7) * (8.0f / 7.0f);
    float rw = (float)(b - 7) * (8.0f / 7.0f);
    const float inv_log2_9 = 0.3154648767971186f;
    float sh = (rh > 0.f) ? 1.f : ((rh < 0.f) ? -1.f : 0.f);
    float sw = (rw > 0.f) ? 1.f : ((rw < 0.f) ? -1.f : 0.f);
    float c0 = sh * log2f(fabsf(rh) + 1.0f) * inv_log2_9;
    float c1 = sw * log2f(fabsf(rw) + 1.0f) * inv_log2_9;
    float acc[8] = {0, 0, 0, 0, 0, 0, 0, 0};
    for (int j = 0; j < 512; ++j) {
      float h = fmaf(c0, w1[2 * j], fmaf(c1, w1[2 * j + 1], b1[j]));
      h = fmaxf(h, 0.0f);
#pragma unroll
      for (int hh = 0; hh < 8; ++hh) acc[hh] = fmaf(h, w2[hh * 512 + j], acc[hh]);
    }
#pragma unroll
    for (int hh = 0; hh < 8; ++hh) cpb_s[t][hh] = 16.0f / (1.0f + expf(-acc[hh]));
  }
  __syncthreads();
  for (int e = t; e < 8 * 64 * 64; e += 256) {
    int h = e >> 12, rem = e & 4095, qi = rem >> 6, kj = rem & 63;
    int dh = (qi >> 3) - (kj >> 3) + 7;
    int dw = (qi & 7) - (kj & 7) + 7;
    biasmat[e] = cpb_s[dh * 15 + dw][h];
  }
}

// ---------------------------------------------------------------------------
// K2: fused per-window QKV + attention.
// 1024 blocks x 256 threads (4 waves). Head-pairs; x staged in k-chunks of 128.
// LDS R0 32KB: [0,16K) xb (QKV phase) aliased by qb(8K)+kb(8K) (attn phase);
//              [16K,24K) vt (V transposed), [24K,32K) ps (P bf16).
// All bf16 tiles XOR-swizzled: byte_in_row ^= (row&7)<<4  (kills stride-128B/256B
// bank conflicts on ds_read_b128 column-slice reads).
// ---------------------------------------------------------------------------
__launch_bounds__(256)
__global__ void fused_kernel(const float* __restrict__ x,
                             const float* __restrict__ mask,
                             const bf16* __restrict__ qkvw_bf,
                             const float* __restrict__ q_bias,
                             const float* __restrict__ v_bias,
                             const float* __restrict__ logit_scale,
                             const float* __restrict__ biasmat,
                             bf16* __restrict__ attn_out) {
  __shared__ __align__(16) char sR0[32768];
  __shared__ float pnorm[2][4][64];
  __shared__ float rnorms[2][64];

  const int tid = threadIdx.x;
  const int w  = tid >> 6;   // wave 0..3
  const int l  = tid & 63;
  const int lg = l >> 4;     // lane group 0..3
  const int lo = l & 15;
  const int b  = blockIdx.x;
  const int widx = b & 63;   // window-in-image for mask

  char* xb   = sR0;           // bf16 [64][128], row stride 256B
  char* qbuf = sR0;           // bf16 [64][64],  row stride 128B
  char* kbuf = sR0 + 8192;
  char* vtb  = sR0 + 16384;   // v^T: [d][token]
  char* psb  = sR0 + 24576;   // P bf16 [64][64]

  const float* xg = x + b * (64 * 512);
  const int ncol = (w << 4) + lo;  // this wave's column (channel) in each matrix

#pragma unroll 1
  for (int hp = 0; hp < 4; ++hp) {
    const int h0 = hp * 2, h1 = hp * 2 + 1;
    // acc[mat][mtile]; mat: 0=q(h0),1=k(h0),2=v(h0),3=q(h1),4=k(h1),5=v(h1)
    f32x4 acc[6][4];
#pragma unroll
    for (int mm = 0; mm < 6; ++mm)
#pragma unroll
      for (int mt = 0; mt < 4; ++mt) { f32x4 z = {0.f, 0.f, 0.f, 0.f}; acc[mm][mt] = z; }

    int rowb[6];
    rowb[0] = h0 * 64 + ncol;        rowb[1] = 512 + h0 * 64 + ncol;
    rowb[2] = 1024 + h0 * 64 + ncol; rowb[3] = h1 * 64 + ncol;
    rowb[4] = 512 + h1 * 64 + ncol;  rowb[5] = 1024 + h1 * 64 + ncol;

    // ---- QKV GEMM: loop k-chunks of 128 ----
#pragma unroll 1
    for (int kc = 0; kc < 4; ++kc) {
      __syncthreads();  // previous users of [0,16K) done
      {
        const int srow = tid >> 2;   // 0..63
        const int sseg = tid & 3;    // 32 floats each
        const float* src = xg + srow * 512 + kc * 128 + sseg * 32;
        char* dstrow = xb + srow * 256;
#pragma unroll
        for (int i = 0; i < 8; ++i) {
          float4 v = *(const float4*)(src + i * 4);
          ushort4 o;
          o.x = f2bf_bits(v.x); o.y = f2bf_bits(v.y);
          o.z = f2bf_bits(v.z); o.w = f2bf_bits(v.w);
          int bir = ((sseg * 64 + i * 8) ^ ((srow & 7) << 4));
          *(ushort4*)(dstrow + bir) = o;
        }
      }
      __syncthreads();
#pragma unroll
      for (int ks = 0; ks < 4; ++ks) {
        bf16x8 af[4];
#pragma unroll
        for (int mt = 0; mt < 4; ++mt) {
          int m = (mt << 4) + lo;
          int bir = ((ks * 64 + (lg << 4)) ^ ((m & 7) << 4));
          af[mt] = *(const bf16x8*)(xb + m * 256 + bir);
        }
        const int kke = kc * 128 + ks * 32 + (lg << 3);
#pragma unroll
        for (int mm = 0; mm < 6; ++mm) {
          bf16x8 bfrag = *(const bf16x8*)(qkvw_bf + rowb[mm] * 512 + kke);
#pragma unroll
          for (int mt = 0; mt < 4; ++mt)
            acc[mm][mt] = MFMA16(af[mt], bfrag, acc[mm][mt]);
        }
      }
    }

    // ---- attention, two heads sequentially ----
#pragma unroll 1
    for (int hh = 0; hh < 2; ++hh) {
      const int h = hp * 2 + hh;
      const float qbv = q_bias[h * 64 + ncol];
      const float vbv = v_bias[h * 64 + ncol];

      // step 1: add biases, per-row sum-of-squares partials (this wave's 16 cols)
#pragma unroll
      for (int mt = 0; mt < 4; ++mt) {
#pragma unroll
        for (int r = 0; r < 4; ++r) {
          float qv = acc[3 * hh + 0][mt][r] + qbv;
          acc[3 * hh + 0][mt][r] = qv;
          float kv = acc[3 * hh + 1][mt][r];
          acc[3 * hh + 2][mt][r] += vbv;
          float q2 = qv * qv, k2 = kv * kv;
#pragma unroll
          for (int s = 1; s < 16; s <<= 1) {
            q2 += __shfl_xor(q2, s, 64);
            k2 += __shfl_xor(k2, s, 64);
          }
          if (lo == 0) {
            int row = (mt << 4) + (lg << 2) + r;
            pnorm[0][w][row] = q2;
            pnorm[1][w][row] = k2;
          }
        }
      }
      __syncthreads();
      // step 2: 1/max(||row||, 1e-12)
      if (tid < 128) {
        int row = tid & 63, m2 = tid >> 6;
        float s = pnorm[m2][0][row] + pnorm[m2][1][row] +
                  pnorm[m2][2][row] + pnorm[m2][3][row];
        rnorms[m2][row] = 1.0f / fmaxf(sqrtf(s), 1e-12f);
      }
      __syncthreads();
      // step 3: write q^,k^ (bf16 swz) and v^T
#pragma unroll
      for (int mt = 0; mt < 4; ++mt) {
#pragma unroll
        for (int r = 0; r < 4; ++r) {
          int row = (mt << 4) + (lg << 2) + r;
          float qn = acc[3 * hh + 0][mt][r] * rnorms[0][row];
          float kn = acc[3 * hh + 1][mt][r] * rnorms[1][row];
          *(bf16*)(qbuf + row * 128 + ((ncol * 2) ^ ((row & 7) << 4))) = (bf16)qn;
          *(bf16*)(kbuf + row * 128 + ((ncol * 2) ^ ((row & 7) << 4))) = (bf16)kn;
          *(bf16*)(vtb + ncol * 128 + ((row * 2) ^ ((ncol & 7) << 4))) =
              (bf16)acc[3 * hh + 2][mt][r];
        }
      }
      __syncthreads();
      // step 4: S = q^ @ k^^T   (wave w owns rows 16w..16w+15, all 64 cols)
      f32x4 sacc[4];
#pragma unroll
      for (int nt = 0; nt < 4; ++nt) { f32x4 z = {0.f, 0.f, 0.f, 0.f}; sacc[nt] = z; }
#pragma unroll
      for (int ks = 0; ks < 2; ++ks) {
        int m = (w << 4) + lo;
        bf16x8 a = *(const bf16x8*)(qbuf + m * 128 +
                                    ((ks * 64 + (lg << 4)) ^ ((m & 7) << 4)));
#pragma unroll
        for (int nt = 0; nt < 4; ++nt) {
          int n = (nt << 4) + lo;
          bf16x8 bb = *(const bf16x8*)(kbuf + n * 128 +
                                       ((ks * 64 + (lg << 4)) ^ ((n & 7) << 4)));
          sacc[nt] = MFMA16(a, bb, sacc[nt]);
        }
      }
      // step 5: scale + bias + mask + softmax (fp32), write P bf16
      float scale = expf(fminf(logit_scale[h], 4.605170185988091f));
      float invl[4];
#pragma unroll
      for (int r = 0; r < 4; ++r) {
        int row = (w << 4) + (lg << 2) + r;
        float sv[4];
#pragma unroll
        for (int nt = 0; nt < 4; ++nt) {
          int col = (nt << 4) + lo;
          float bm = biasmat[(h << 12) + (row << 6) + col] +
                     mask[(widx << 12) + (row << 6) + col];
          sv[nt] = fmaf(sacc[nt][r], scale, bm);
        }
        float mr = fmaxf(fmaxf(sv[0], sv[1]), fmaxf(sv[2], sv[3]));
#pragma unroll
        for (int s = 1; s < 16; s <<= 1) mr = fmaxf(mr, __shfl_xor(mr, s, 64));
        float lsum = 0.f;
#pragma unroll
        for (int nt = 0; nt < 4; ++nt) { sv[nt] = expf(sv[nt] - mr); lsum += sv[nt]; }
#pragma unroll
        for (int s = 1; s < 16; s <<= 1) lsum += __shfl_xor(lsum, s, 64);
        invl[r] = 1.0f / lsum;
#pragma unroll
        for (int nt = 0; nt < 4; ++nt) {
          int col = (nt << 4) + lo;
          *(bf16*)(psb + row * 128 + ((col * 2) ^ ((row & 7) << 4))) = (bf16)sv[nt];
        }
      }
      __syncthreads();
      // step 6: O = P @ V  (B-operand from v^T rows)
      f32x4 oacc[4];
#pragma unroll
      for (int nt = 0; nt < 4; ++nt) { f32x4 z = {0.f, 0.f, 0.f, 0.f}; oacc[nt] = z; }
#pragma unroll
      for (int ks = 0; ks < 2; ++ks) {
        int m = (w << 4) + lo;
        bf16x8 a = *(const bf16x8*)(psb + m * 128 +
                                    ((ks * 64 + (lg << 4)) ^ ((m & 7) << 4)));
#pragma unroll
        for (int nt = 0; nt < 4; ++nt) {
          int d = (nt << 4) + lo;
          bf16x8 bb = *(const bf16x8*)(vtb + d * 128 +
                                       ((ks * 64 + (lg << 4)) ^ ((d & 7) << 4)));
          oacc[nt] = MFMA16(a, bb, oacc[nt]);
        }
      }
      // step 7: store attn_out bf16 (normalize by row softmax denom)
#pragma unroll
      for (int r = 0; r < 4; ++r) {
        int row = (w << 4) + (lg << 2) + r;
#pragma unroll
        for (int nt = 0; nt < 4; ++nt) {
          int d = (nt << 4) + lo;
          attn_out[(b * 64 + row) * 512 + h * 64 + d] = (bf16)(oacc[nt][r] * invl[r]);
        }
      }
    }  // hh
  }    // hp
}

// ---------------------------------------------------------------------------
// K3: proj GEMM. out[65536x512] = attn(bf16) @ proj_w^T(bf16) + proj_b, f32 out.
// 128x128 tile, BK=64, 4 waves in 2x2 quadrants.
// ---------------------------------------------------------------------------
__launch_bounds__(256)
__global__ void proj_kernel(const bf16* __restrict__ attn_in,
                            const bf16* __restrict__ projw_bf,
                            const float* __restrict__ proj_b,
                            float* __restrict__ out) {
  __shared__ __align__(16) char As[16384];
  __shared__ __align__(16) char Bs[16384];
  const int tid = threadIdx.x;
  const int w = tid >> 6, l = tid & 63, lg = l >> 4, lo = l & 15;
  const int wm = w >> 1, wn = w & 1;
  const int m0 = (blockIdx.x >> 2) * 128;
  const int n0 = (blockIdx.x & 3) * 128;

  f32x4 acc[4][4];
#pragma unroll
  for (int mt = 0; mt < 4; ++mt)
#pragma unroll
    for (int nt = 0; nt < 4; ++nt) { f32x4 z = {0.f, 0.f, 0.f, 0.f}; acc[mt][nt] = z; }

#pragma unroll 1
  for (int kc = 0; kc < 8; ++kc) {
    __syncthreads();
    {
      const int srow = tid >> 1, sseg = tid & 1;  // 2 threads/row, 32 elems each
      const bf16* srcA = attn_in + (m0 + srow) * 512 + kc * 64 + sseg * 32;
      const bf16* srcB = projw_bf + (n0 + srow) * 512 + kc * 64 + sseg * 32;
#pragma unroll
      for (int i = 0; i < 4; ++i) {
        uint4 a4 = *(const uint4*)(srcA + i * 8);
        uint4 b4 = *(const uint4*)(srcB + i * 8);
        int bir = ((sseg * 64 + i * 16) ^ ((srow & 7) << 4));
        *(uint4*)(As + srow * 128 + bir) = a4;
        *(uint4*)(Bs + srow * 128 + bir) = b4;
      }
    }
    __syncthreads();
#pragma unroll
    for (int ks = 0; ks < 2; ++ks) {
      bf16x8 af[4], bfv[4];
#pragma unroll
      for (int mt = 0; mt < 4; ++mt) {
        int m = (wm << 6) + (mt << 4) + lo;
        af[mt] = *(const bf16x8*)(As + m * 128 +
                                  ((ks * 64 + (lg << 4)) ^ ((m & 7) << 4)));
      }
#pragma unroll
      for (int nt = 0; nt < 4; ++nt) {
        int n = (wn << 6) + (nt << 4) + lo;
        bfv[nt] = *(const bf16x8*)(Bs + n * 128 +
                                   ((ks * 64 + (lg << 4)) ^ ((n & 7) << 4)));
      }
#pragma unroll
      for (int mt = 0; mt < 4; ++mt)
#pragma unroll
        for (int nt = 0; nt < 4; ++nt)
          acc[mt][nt] = MFMA16(af[mt], bfv[nt], acc[mt][nt]);
    }
  }
#pragma unroll
  for (int nt = 0; nt < 4; ++nt) {
    int col = n0 + (wn << 6) + (nt << 4) + lo;
    float pb = proj_b[col];
#pragma unroll
    for (int mt = 0; mt < 4; ++mt) {
#pragma unroll
      for (int r = 0; r < 4; ++r) {
        int row = m0 + (wm << 6) + (mt << 4) + (lg << 2) + r;
        out[row * 512 + col] = acc[mt][nt][r] + pb;
      }
    }
  }
}

// ---------------------------------------------------------------------------
extern "C" void kernel_launch(void* const* d_in, const int* in_sizes, int n_in,
                              void* d_out, int out_size, void* d_ws, size_t ws_size,
                              hipStream_t stream) {
  const float* x       = (const float*)d_in[0];
  const float* mask    = (const float*)d_in[1];
  const float* qkvw    = (const float*)d_in[2];
  const float* q_bias  = (const float*)d_in[3];
  const float* v_bias  = (const float*)d_in[4];
  const float* ls      = (const float*)d_in[5];
  const float* cpb_w1  = (const float*)d_in[6];
  const float* cpb_b1  = (const float*)d_in[7];
  const float* cpb_w2  = (const float*)d_in[8];
  const float* proj_w  = (const float*)d_in[9];
  const float* proj_b  = (const float*)d_in[10];
  float* out = (float*)d_out;
  char* ws = (char*)d_ws;

  float* biasmat = (float*)(ws + OFF_BIAS);
  bf16* qkvw_bf  = (bf16*)(ws + OFF_QKVW);
  bf16* projw_bf = (bf16*)(ws + OFF_PROJW);
  bf16* attn     = (bf16*)(ws + OFF_ATTN);

  hipLaunchKernelGGL(wconv_kernel, dim3(256), dim3(256), 0, stream,
                     qkvw, proj_w, qkvw_bf, projw_bf);
  hipLaunchKernelGGL(cpb_kernel, dim3(1), dim3(256), 0, stream,
                     cpb_w1, cpb_b1, cpb_w2, biasmat);
  hipLaunchKernelGGL(fused_kernel, dim3(1024), dim3(256), 0, stream,
                     x, mask, qkvw_bf, q_bias, v_bias, ls, biasmat, attn);
  hipLaunchKernelGGL(proj_kernel, dim3(2048), dim3(256), 0, stream,
                     attn, projw_bf, proj_b, out);
}

// Round 2
// 879.031 us; speedup vs baseline: 2.0758x; 2.0758x over previous
//
#include <hip/hip_runtime.h>

// ---------------------------------------------------------------------------
// Swin-V2 window attention, MI355X (gfx950).
// B=1024 windows, N=64 tokens, C=512, NH=8 heads, HD=64.
// Structure:
//   K0 wconv : qkv_w / proj_w f32 -> bf16 (ws)
//   K1 cpb   : continuous rel-pos-bias MLP -> bias table [8][64][64] f32 (ws)
//   K2 fused : per-window  QKV(MFMA bf16) + cosine-attn (fp32 softmax,
//              QK^T & PV via MFMA bf16) -> attn_out bf16 (ws)
//   K3 proj  : [65536x512] @ [512x512]^T + bias -> out f32
//
// R1 fix: the head loop (hh) was `#pragma unroll 1`, making acc[3*hh+..]
// runtime-indexed -> entire 96-reg accumulator spilled to scratch
// (WRITE_SIZE 6.8 GB, 4.4 TB/s of scratch traffic, MfmaUtil 2.9%).
// Now fully unrolled so all ext_vector array indices are compile-time.
// ---------------------------------------------------------------------------

typedef __bf16 bf16;
typedef bf16  bf16x8 __attribute__((ext_vector_type(8)));
typedef float f32x4  __attribute__((ext_vector_type(4)));

#define MFMA16(a, b, c) __builtin_amdgcn_mfma_f32_16x16x32_bf16((a), (b), (c), 0, 0, 0)

__device__ __forceinline__ unsigned short f2bf_bits(float f) {
  return __builtin_bit_cast(unsigned short, (bf16)f);
}

// ws layout (bytes)
#define OFF_BIAS   0          // 8*64*64*4   = 131072
#define OFF_QKVW   131072     // 1536*512*2  = 1572864
#define OFF_PROJW  1703936    // 512*512*2   = 524288
#define OFF_ATTN   2228224    // 65536*512*2 = 67108864  (total ~66.2 MB)

// ---------------------------------------------------------------------------
// K0: weight conversion f32 -> bf16. 262144 float4 total (qkv: 196608, proj: 65536)
// ---------------------------------------------------------------------------
__global__ void wconv_kernel(const float* __restrict__ qkvw,
                             const float* __restrict__ projw,
                             bf16* __restrict__ qkvw_bf,
                             bf16* __restrict__ projw_bf) {
  int i = blockIdx.x * 256 + threadIdx.x;
#pragma unroll
  for (int it = 0; it < 4; ++it) {
    int idx = i + it * 65536;
    const float4* src;
    bf16* dst;
    if (idx < 196608) {
      src = ((const float4*)qkvw) + idx;
      dst = qkvw_bf + idx * 4;
    } else {
      int j = idx - 196608;
      src = ((const float4*)projw) + j;
      dst = projw_bf + j * 4;
    }
    float4 v = *src;
    ushort4 o;
    o.x = f2bf_bits(v.x); o.y = f2bf_bits(v.y);
    o.z = f2bf_bits(v.z); o.w = f2bf_bits(v.w);
    *(ushort4*)dst = o;
  }
}

// ---------------------------------------------------------------------------
// K1: CPB bias table. rel coords / rel idx recomputed in-kernel (module consts).
// biasmat[h][qi][kj] = 16*sigmoid( relu(coords @ w1^T + b1) @ w2^T )[relidx][h]
// ---------------------------------------------------------------------------
__global__ void cpb_kernel(const float* __restrict__ w1, const float* __restrict__ b1,
                           const float* __restrict__ w2, float* __restrict__ biasmat) {
  __shared__ float cpb_s[225][8];
  int t = threadIdx.x;
  if (t < 225) {
    int a = t / 15, b = t % 15;
    float rh = (float)(a - 7) * (8.0f / 7.0f);
    float rw = (float)(b - 7) * (8.0f / 7.0f);
    const float inv_log2_9 = 0.3154648767971186f;
    float sh = (rh > 0.f) ? 1.f : ((rh < 0.f) ? -1.f : 0.f);
    float sw = (rw > 0.f) ? 1.f : ((rw < 0.f) ? -1.f : 0.f);
    float c0 = sh * log2f(fabsf(rh) + 1.0f) * inv_log2_9;
    float c1 = sw * log2f(fabsf(rw) + 1.0f) * inv_log2_9;
    float acc[8] = {0, 0, 0, 0, 0, 0, 0, 0};
    for (int j = 0; j < 512; ++j) {
      float h = fmaf(c0, w1[2 * j], fmaf(c1, w1[2 * j + 1], b1[j]));
      h = fmaxf(h, 0.0f);
#pragma unroll
      for (int hh = 0; hh < 8; ++hh) acc[hh] = fmaf(h, w2[hh * 512 + j], acc[hh]);
    }
#pragma unroll
    for (int hh = 0; hh < 8; ++hh) cpb_s[t][hh] = 16.0f / (1.0f + expf(-acc[hh]));
  }
  __syncthreads();
  for (int e = t; e < 8 * 64 * 64; e += 256) {
    int h = e >> 12, rem = e & 4095, qi = rem >> 6, kj = rem & 63;
    int dh = (qi >> 3) - (kj >> 3) + 7;
    int dw = (qi & 7) - (kj & 7) + 7;
    biasmat[e] = cpb_s[dh * 15 + dw][h];
  }
}

// ---------------------------------------------------------------------------
// K2: fused per-window QKV + attention.
// 1024 blocks x 256 threads (4 waves). Head-pairs; x staged in k-chunks of 128.
// LDS R0 32KB: [0,16K) xb (QKV phase) aliased by qb(8K)+kb(8K) (attn phase);
//              [16K,24K) vt (V transposed), [24K,32K) ps (P bf16).
// All bf16 tiles XOR-swizzled: byte_in_row ^= (row&7)<<4.
// ---------------------------------------------------------------------------
__launch_bounds__(256)
__global__ void fused_kernel(const float* __restrict__ x,
                             const float* __restrict__ mask,
                             const bf16* __restrict__ qkvw_bf,
                             const float* __restrict__ q_bias,
                             const float* __restrict__ v_bias,
                             const float* __restrict__ logit_scale,
                             const float* __restrict__ biasmat,
                             bf16* __restrict__ attn_out) {
  __shared__ __align__(16) char sR0[32768];
  __shared__ float pnorm[2][4][64];
  __shared__ float rnorms[2][64];

  const int tid = threadIdx.x;
  const int w  = tid >> 6;   // wave 0..3
  const int l  = tid & 63;
  const int lg = l >> 4;     // lane group 0..3
  const int lo = l & 15;
  const int b  = blockIdx.x;
  const int widx = b & 63;   // window-in-image for mask

  char* xb   = sR0;           // bf16 [64][128], row stride 256B
  char* qbuf = sR0;           // bf16 [64][64],  row stride 128B
  char* kbuf = sR0 + 8192;
  char* vtb  = sR0 + 16384;   // v^T: [d][token]
  char* psb  = sR0 + 24576;   // P bf16 [64][64]

  const float* xg = x + b * (64 * 512);
  const int ncol = (w << 4) + lo;  // this wave's column (channel) in each matrix

#pragma unroll 1
  for (int hp = 0; hp < 4; ++hp) {
    const int h0 = hp * 2, h1 = hp * 2 + 1;
    // acc[mat][mtile]; mat: 0=q(h0),1=k(h0),2=v(h0),3=q(h1),4=k(h1),5=v(h1)
    f32x4 acc[6][4];
#pragma unroll
    for (int mm = 0; mm < 6; ++mm)
#pragma unroll
      for (int mt = 0; mt < 4; ++mt) { f32x4 z = {0.f, 0.f, 0.f, 0.f}; acc[mm][mt] = z; }

    int rowb[6];
    rowb[0] = h0 * 64 + ncol;        rowb[1] = 512 + h0 * 64 + ncol;
    rowb[2] = 1024 + h0 * 64 + ncol; rowb[3] = h1 * 64 + ncol;
    rowb[4] = 512 + h1 * 64 + ncol;  rowb[5] = 1024 + h1 * 64 + ncol;

    // ---- QKV GEMM: loop k-chunks of 128 ----
#pragma unroll 1
    for (int kc = 0; kc < 4; ++kc) {
      __syncthreads();  // previous users of [0,16K) done
      {
        const int srow = tid >> 2;   // 0..63
        const int sseg = tid & 3;    // 32 floats each
        const float* src = xg + srow * 512 + kc * 128 + sseg * 32;
        char* dstrow = xb + srow * 256;
#pragma unroll
        for (int i = 0; i < 8; ++i) {
          float4 v = *(const float4*)(src + i * 4);
          ushort4 o;
          o.x = f2bf_bits(v.x); o.y = f2bf_bits(v.y);
          o.z = f2bf_bits(v.z); o.w = f2bf_bits(v.w);
          int bir = ((sseg * 64 + i * 8) ^ ((srow & 7) << 4));
          *(ushort4*)(dstrow + bir) = o;
        }
      }
      __syncthreads();
#pragma unroll
      for (int ks = 0; ks < 4; ++ks) {
        bf16x8 af[4];
#pragma unroll
        for (int mt = 0; mt < 4; ++mt) {
          int m = (mt << 4) + lo;
          int bir = ((ks * 64 + (lg << 4)) ^ ((m & 7) << 4));
          af[mt] = *(const bf16x8*)(xb + m * 256 + bir);
        }
        const int kke = kc * 128 + ks * 32 + (lg << 3);
#pragma unroll
        for (int mm = 0; mm < 6; ++mm) {
          bf16x8 bfrag = *(const bf16x8*)(qkvw_bf + rowb[mm] * 512 + kke);
#pragma unroll
          for (int mt = 0; mt < 4; ++mt)
            acc[mm][mt] = MFMA16(af[mt], bfrag, acc[mm][mt]);
        }
      }
    }

    // ---- attention, two heads sequentially (FULLY UNROLLED: all acc
    //      indices must be compile-time constants, else acc -> scratch) ----
#pragma unroll
    for (int hh = 0; hh < 2; ++hh) {
      const int h = hp * 2 + hh;
      const float qbv = q_bias[h * 64 + ncol];
      const float vbv = v_bias[h * 64 + ncol];

      // step 1: add biases, per-row sum-of-squares partials (this wave's 16 cols)
#pragma unroll
      for (int mt = 0; mt < 4; ++mt) {
#pragma unroll
        for (int r = 0; r < 4; ++r) {
          float qv = acc[3 * hh + 0][mt][r] + qbv;
          acc[3 * hh + 0][mt][r] = qv;
          float kv = acc[3 * hh + 1][mt][r];
          acc[3 * hh + 2][mt][r] += vbv;
          float q2 = qv * qv, k2 = kv * kv;
#pragma unroll
          for (int s = 1; s < 16; s <<= 1) {
            q2 += __shfl_xor(q2, s, 64);
            k2 += __shfl_xor(k2, s, 64);
          }
          if (lo == 0) {
            int row = (mt << 4) + (lg << 2) + r;
            pnorm[0][w][row] = q2;
            pnorm[1][w][row] = k2;
          }
        }
      }
      __syncthreads();
      // step 2: 1/max(||row||, 1e-12)
      if (tid < 128) {
        int row = tid & 63, m2 = tid >> 6;
        float s = pnorm[m2][0][row] + pnorm[m2][1][row] +
                  pnorm[m2][2][row] + pnorm[m2][3][row];
        rnorms[m2][row] = 1.0f / fmaxf(sqrtf(s), 1e-12f);
      }
      __syncthreads();
      // step 3: write q^,k^ (bf16 swz) and v^T
#pragma unroll
      for (int mt = 0; mt < 4; ++mt) {
#pragma unroll
        for (int r = 0; r < 4; ++r) {
          int row = (mt << 4) + (lg << 2) + r;
          float qn = acc[3 * hh + 0][mt][r] * rnorms[0][row];
          float kn = acc[3 * hh + 1][mt][r] * rnorms[1][row];
          *(bf16*)(qbuf + row * 128 + ((ncol * 2) ^ ((row & 7) << 4))) = (bf16)qn;
          *(bf16*)(kbuf + row * 128 + ((ncol * 2) ^ ((row & 7) << 4))) = (bf16)kn;
          *(bf16*)(vtb + ncol * 128 + ((row * 2) ^ ((ncol & 7) << 4))) =
              (bf16)acc[3 * hh + 2][mt][r];
        }
      }
      __syncthreads();
      // step 4: S = q^ @ k^^T   (wave w owns rows 16w..16w+15, all 64 cols)
      f32x4 sacc[4];
#pragma unroll
      for (int nt = 0; nt < 4; ++nt) { f32x4 z = {0.f, 0.f, 0.f, 0.f}; sacc[nt] = z; }
#pragma unroll
      for (int ks = 0; ks < 2; ++ks) {
        int m = (w << 4) + lo;
        bf16x8 a = *(const bf16x8*)(qbuf + m * 128 +
                                    ((ks * 64 + (lg << 4)) ^ ((m & 7) << 4)));
#pragma unroll
        for (int nt = 0; nt < 4; ++nt) {
          int n = (nt << 4) + lo;
          bf16x8 bb = *(const bf16x8*)(kbuf + n * 128 +
                                       ((ks * 64 + (lg << 4)) ^ ((n & 7) << 4)));
          sacc[nt] = MFMA16(a, bb, sacc[nt]);
        }
      }
      // step 5: scale + bias + mask + softmax (fp32), write P bf16
      float scale = expf(fminf(logit_scale[h], 4.605170185988091f));
      float invl[4];
#pragma unroll
      for (int r = 0; r < 4; ++r) {
        int row = (w << 4) + (lg << 2) + r;
        float sv[4];
#pragma unroll
        for (int nt = 0; nt < 4; ++nt) {
          int col = (nt << 4) + lo;
          float bm = biasmat[(h << 12) + (row << 6) + col] +
                     mask[(widx << 12) + (row << 6) + col];
          sv[nt] = fmaf(sacc[nt][r], scale, bm);
        }
        float mr = fmaxf(fmaxf(sv[0], sv[1]), fmaxf(sv[2], sv[3]));
#pragma unroll
        for (int s = 1; s < 16; s <<= 1) mr = fmaxf(mr, __shfl_xor(mr, s, 64));
        float lsum = 0.f;
#pragma unroll
        for (int nt = 0; nt < 4; ++nt) { sv[nt] = expf(sv[nt] - mr); lsum += sv[nt]; }
#pragma unroll
        for (int s = 1; s < 16; s <<= 1) lsum += __shfl_xor(lsum, s, 64);
        invl[r] = 1.0f / lsum;
#pragma unroll
        for (int nt = 0; nt < 4; ++nt) {
          int col = (nt << 4) + lo;
          *(bf16*)(psb + row * 128 + ((col * 2) ^ ((row & 7) << 4))) = (bf16)sv[nt];
        }
      }
      __syncthreads();
      // step 6: O = P @ V  (B-operand from v^T rows)
      f32x4 oacc[4];
#pragma unroll
      for (int nt = 0; nt < 4; ++nt) { f32x4 z = {0.f, 0.f, 0.f, 0.f}; oacc[nt] = z; }
#pragma unroll
      for (int ks = 0; ks < 2; ++ks) {
        int m = (w << 4) + lo;
        bf16x8 a = *(const bf16x8*)(psb + m * 128 +
                                    ((ks * 64 + (lg << 4)) ^ ((m & 7) << 4)));
#pragma unroll
        for (int nt = 0; nt < 4; ++nt) {
          int d = (nt << 4) + lo;
          bf16x8 bb = *(const bf16x8*)(vtb + d * 128 +
                                       ((ks * 64 + (lg << 4)) ^ ((d & 7) << 4)));
          oacc[nt] = MFMA16(a, bb, oacc[nt]);
        }
      }
      // step 7: store attn_out bf16 (normalize by row softmax denom)
#pragma unroll
      for (int r = 0; r < 4; ++r) {
        int row = (w << 4) + (lg << 2) + r;
#pragma unroll
        for (int nt = 0; nt < 4; ++nt) {
          int d = (nt << 4) + lo;
          attn_out[(b * 64 + row) * 512 + h * 64 + d] = (bf16)(oacc[nt][r] * invl[r]);
        }
      }
    }  // hh
  }    // hp
}

// ---------------------------------------------------------------------------
// K3: proj GEMM. out[65536x512] = attn(bf16) @ proj_w^T(bf16) + proj_b, f32 out.
// 128x128 tile, BK=64, 4 waves in 2x2 quadrants.
// ---------------------------------------------------------------------------
__launch_bounds__(256)
__global__ void proj_kernel(const bf16* __restrict__ attn_in,
                            const bf16* __restrict__ projw_bf,
                            const float* __restrict__ proj_b,
                            float* __restrict__ out) {
  __shared__ __align__(16) char As[16384];
  __shared__ __align__(16) char Bs[16384];
  const int tid = threadIdx.x;
  const int w = tid >> 6, l = tid & 63, lg = l >> 4, lo = l & 15;
  const int wm = w >> 1, wn = w & 1;
  const int m0 = (blockIdx.x >> 2) * 128;
  const int n0 = (blockIdx.x & 3) * 128;

  f32x4 acc[4][4];
#pragma unroll
  for (int mt = 0; mt < 4; ++mt)
#pragma unroll
    for (int nt = 0; nt < 4; ++nt) { f32x4 z = {0.f, 0.f, 0.f, 0.f}; acc[mt][nt] = z; }

#pragma unroll 1
  for (int kc = 0; kc < 8; ++kc) {
    __syncthreads();
    {
      const int srow = tid >> 1, sseg = tid & 1;  // 2 threads/row, 32 elems each
      const bf16* srcA = attn_in + (m0 + srow) * 512 + kc * 64 + sseg * 32;
      const bf16* srcB = projw_bf + (n0 + srow) * 512 + kc * 64 + sseg * 32;
#pragma unroll
      for (int i = 0; i < 4; ++i) {
        uint4 a4 = *(const uint4*)(srcA + i * 8);
        uint4 b4 = *(const uint4*)(srcB + i * 8);
        int bir = ((sseg * 64 + i * 16) ^ ((srow & 7) << 4));
        *(uint4*)(As + srow * 128 + bir) = a4;
        *(uint4*)(Bs + srow * 128 + bir) = b4;
      }
    }
    __syncthreads();
#pragma unroll
    for (int ks = 0; ks < 2; ++ks) {
      bf16x8 af[4], bfv[4];
#pragma unroll
      for (int mt = 0; mt < 4; ++mt) {
        int m = (wm << 6) + (mt << 4) + lo;
        af[mt] = *(const bf16x8*)(As + m * 128 +
                                  ((ks * 64 + (lg << 4)) ^ ((m & 7) << 4)));
      }
#pragma unroll
      for (int nt = 0; nt < 4; ++nt) {
        int n = (wn << 6) + (nt << 4) + lo;
        bfv[nt] = *(const bf16x8*)(Bs + n * 128 +
                                   ((ks * 64 + (lg << 4)) ^ ((n & 7) << 4)));
      }
#pragma unroll
      for (int mt = 0; mt < 4; ++mt)
#pragma unroll
        for (int nt = 0; nt < 4; ++nt)
          acc[mt][nt] = MFMA16(af[mt], bfv[nt], acc[mt][nt]);
    }
  }
#pragma unroll
  for (int nt = 0; nt < 4; ++nt) {
    int col = n0 + (wn << 6) + (nt << 4) + lo;
    float pb = proj_b[col];
#pragma unroll
    for (int mt = 0; mt < 4; ++mt) {
#pragma unroll
      for (int r = 0; r < 4; ++r) {
        int row = m0 + (wm << 6) + (mt << 4) + (lg << 2) + r;
        out[row * 512 + col] = acc[mt][nt][r] + pb;
      }
    }
  }
}

// ---------------------------------------------------------------------------
extern "C" void kernel_launch(void* const* d_in, const int* in_sizes, int n_in,
                              void* d_out, int out_size, void* d_ws, size_t ws_size,
                              hipStream_t stream) {
  const float* x       = (const float*)d_in[0];
  const float* mask    = (const float*)d_in[1];
  const float* qkvw    = (const float*)d_in[2];
  const float* q_bias  = (const float*)d_in[3];
  const float* v_bias  = (const float*)d_in[4];
  const float* ls      = (const float*)d_in[5];
  const float* cpb_w1  = (const float*)d_in[6];
  const float* cpb_b1  = (const float*)d_in[7];
  const float* cpb_w2  = (const float*)d_in[8];
  const float* proj_w  = (const float*)d_in[9];
  const float* proj_b  = (const float*)d_in[10];
  float* out = (float*)d_out;
  char* ws = (char*)d_ws;

  float* biasmat = (float*)(ws + OFF_BIAS);
  bf16* qkvw_bf  = (bf16*)(ws + OFF_QKVW);
  bf16* projw_bf = (bf16*)(ws + OFF_PROJW);
  bf16* attn     = (bf16*)(ws + OFF_ATTN);

  hipLaunchKernelGGL(wconv_kernel, dim3(256), dim3(256), 0, stream,
                     qkvw, proj_w, qkvw_bf, projw_bf);
  hipLaunchKernelGGL(cpb_kernel, dim3(1), dim3(256), 0, stream,
                     cpb_w1, cpb_b1, cpb_w2, biasmat);
  hipLaunchKernelGGL(fused_kernel, dim3(1024), dim3(256), 0, stream,
                     x, mask, qkvw_bf, q_bias, v_bias, ls, biasmat, attn);
  hipLaunchKernelGGL(proj_kernel, dim3(2048), dim3(256), 0, stream,
                     attn, projw_bf, proj_b, out);
}

// Round 3
// 576.370 us; speedup vs baseline: 3.1658x; 1.5251x over previous
//
#include <hip/hip_runtime.h>

// ---------------------------------------------------------------------------
// Swin-V2 window attention, MI355X (gfx950).
// B=1024 windows, N=64 tokens, C=512, NH=8 heads, HD=64.
//
// R3 restructure: the per-window fused kernel was latency-bound (MfmaUtil 7.5%,
// 60+ barriers/block, 2 blocks/CU). Split into GEMM-shaped kernels:
//   K0 wconv : qkv_w/proj_w f32 -> bf16 PRE-SWIZZLED [nb][kc][128][64] tiles
//   K1 cpb   : rel-pos MLP -> cpb_small[225][8] f32
//   K2 qkv   : [65536x1536] GEMM + fused bias/normalize epilogue
//              -> qhat,khat [win,h,tok,d], vT [win,h,d,tok] bf16
//   K3 attn  : per (window,head-wave): QK MFMA + fp32 softmax + PV MFMA
//              -> attn in pre-swizzled proj-A-tile layout
//   K4 proj  : [65536x512]@[512x512]^T, both operands via global_load_lds
//              from pre-swizzled tiles (conflict-free swizzled ds_read)
// ---------------------------------------------------------------------------

typedef __bf16 bf16;
typedef bf16  bf16x8 __attribute__((ext_vector_type(8)));
typedef float f32x4  __attribute__((ext_vector_type(4)));

#define MFMA16(a, b, c) __builtin_amdgcn_mfma_f32_16x16x32_bf16((a), (b), (c), 0, 0, 0)

__device__ __forceinline__ unsigned short f2bf_bits(float f) {
  return __builtin_bit_cast(unsigned short, (bf16)f);
}

__device__ __forceinline__ void gload_lds16(const void* g, void* l) {
  __builtin_amdgcn_global_load_lds(
      (const __attribute__((address_space(1))) void*)g,
      (__attribute__((address_space(3))) void*)l, 16, 0, 0);
}

// ws layout (bytes)
#define OFF_CPB     0u           // 225*8*4 = 7200, pad to 8192
#define OFF_QKVWT   8192u        // 12*8*16384 = 1572864
#define OFF_PROJWT  1581056u     // 4*8*16384  = 524288
#define OFF_QHAT    2105344u     // 67108864
#define OFF_KHAT    69214208u    // 67108864
#define OFF_VT      136323072u   // 67108864
#define OFF_ATTN    203431936u   // 512*8*16384 = 67108864  (total ~258 MB)

// ---------------------------------------------------------------------------
// K0: weights f32 -> bf16 pre-swizzled tiles [nb][kc][n 128][k 64],
// byte(n,k) = n*128 + ((k*2) ^ ((n&7)<<4)).  8B store granularity keeps
// the XOR (bits 4-6) alignment-safe.
// ---------------------------------------------------------------------------
__global__ void wconv_kernel(const float* __restrict__ qkvw,
                             const float* __restrict__ projw,
                             char* __restrict__ ws) {
  int i = blockIdx.x * 256 + threadIdx.x;
#pragma unroll
  for (int it = 0; it < 4; ++it) {
    int idx = i + it * 65536;  // ushort4 index; 262144 total
    const float* src;
    unsigned base;
    int row, c4;
    if (idx < 196608) {               // qkvw [1536][512]
      row = idx >> 7; c4 = idx & 127;
      src = qkvw + row * 512 + c4 * 4;
      base = OFF_QKVWT + (unsigned)(((row >> 7) * 8 + (c4 >> 4)) << 14);
    } else {                          // projw [512][512]
      int j = idx - 196608;
      row = j >> 7; c4 = j & 127;
      src = projw + row * 512 + c4 * 4;
      base = OFF_PROJWT + (unsigned)(((row >> 7) * 8 + (c4 >> 4)) << 14);
    }
    int n = row & 127;
    int kb = (c4 & 15) * 8;           // byte offset of k within 128B row
    float4 v = *(const float4*)src;
    ushort4 o;
    o.x = f2bf_bits(v.x); o.y = f2bf_bits(v.y);
    o.z = f2bf_bits(v.z); o.w = f2bf_bits(v.w);
    *(ushort4*)(ws + base + n * 128 + (kb ^ ((n & 7) << 4))) = o;
  }
}

// ---------------------------------------------------------------------------
// K1: CPB MLP -> cpb_small[225][8].  225 blocks, 256 threads reduce over j.
// ---------------------------------------------------------------------------
__global__ void cpb_kernel(const float* __restrict__ w1, const float* __restrict__ b1,
                           const float* __restrict__ w2, float* __restrict__ cpb_small) {
  const int t = blockIdx.x;     // rel-pos index 0..224
  const int tid = threadIdx.x;
  const int a = t / 15, bb = t % 15;
  const float rh = (float)(a - 7) * (8.0f / 7.0f);
  const float rw = (float)(bb - 7) * (8.0f / 7.0f);
  const float inv_log2_9 = 0.3154648767971186f;
  float sh = (rh > 0.f) ? 1.f : ((rh < 0.f) ? -1.f : 0.f);
  float sw = (rw > 0.f) ? 1.f : ((rw < 0.f) ? -1.f : 0.f);
  float c0 = sh * log2f(fabsf(rh) + 1.0f) * inv_log2_9;
  float c1 = sw * log2f(fabsf(rw) + 1.0f) * inv_log2_9;
  float acc[8] = {0, 0, 0, 0, 0, 0, 0, 0};
  for (int j = tid; j < 512; j += 256) {
    float hv = fmaf(c0, w1[2 * j], fmaf(c1, w1[2 * j + 1], b1[j]));
    hv = fmaxf(hv, 0.0f);
#pragma unroll
    for (int hh = 0; hh < 8; ++hh) acc[hh] = fmaf(hv, w2[hh * 512 + j], acc[hh]);
  }
#pragma unroll
  for (int hh = 0; hh < 8; ++hh)
#pragma unroll
    for (int s = 1; s < 64; s <<= 1) acc[hh] += __shfl_xor(acc[hh], s, 64);
  __shared__ float wsum[4][8];
  if ((tid & 63) == 0) {
#pragma unroll
    for (int hh = 0; hh < 8; ++hh) wsum[tid >> 6][hh] = acc[hh];
  }
  __syncthreads();
  if (tid < 8) {
    float s = wsum[0][tid] + wsum[1][tid] + wsum[2][tid] + wsum[3][tid];
    cpb_small[t * 8 + tid] = 16.0f / (1.0f + expf(-s));
  }
}

// ---------------------------------------------------------------------------
// K2: QKV GEMM [65536 x 1536], K=512.  128x128 tile, BK=64, 4 waves 2x2.
// A: x f32 reg-staged -> bf16 swizzled LDS.  B: global_load_lds from
// pre-swizzled weight tiles.  Epilogue: bias + per-row q/k normalize
// (in-wave: a head's 64 cols == one wave's 64 cols) + scatter stores.
// ---------------------------------------------------------------------------
__launch_bounds__(256)
__global__ void qkv_gemm(const float* __restrict__ x,
                         const float* __restrict__ q_bias,
                         const float* __restrict__ v_bias,
                         char* __restrict__ ws) {
  __shared__ __align__(16) char As[16384];
  __shared__ __align__(16) char Bs[16384];
  const int tid = threadIdx.x;
  const int w = tid >> 6, l = tid & 63, lg = l >> 4, lo = l & 15;
  const int wm = w >> 1, wn = w & 1;
  const int bid = blockIdx.x;
  const int wg = (bid & 7) * 768 + (bid >> 3);   // XCD-contiguous (6144 % 8 == 0)
  const int mb = wg / 12, nb = wg % 12;

  const float* xg = x + (size_t)mb * (128 * 512);
  const char* bt_base = ws + OFF_QKVWT + (unsigned)(nb * 8 << 14);

  f32x4 acc[4][4];
#pragma unroll
  for (int mt = 0; mt < 4; ++mt)
#pragma unroll
    for (int nt = 0; nt < 4; ++nt) { f32x4 z = {0.f, 0.f, 0.f, 0.f}; acc[mt][nt] = z; }

#pragma unroll 1
  for (int kc = 0; kc < 8; ++kc) {
    __syncthreads();
    // stage A: 128 rows x 64 k f32 -> bf16 swizzled
#pragma unroll
    for (int i = 0; i < 8; ++i) {
      int f = i * 256 + tid;
      int row = f >> 4, c4 = f & 15;
      float4 v = *(const float4*)(xg + row * 512 + kc * 64 + c4 * 4);
      ushort4 o;
      o.x = f2bf_bits(v.x); o.y = f2bf_bits(v.y);
      o.z = f2bf_bits(v.z); o.w = f2bf_bits(v.w);
      *(ushort4*)(As + row * 128 + ((c4 * 8) ^ ((row & 7) << 4))) = o;
    }
    // stage B: verbatim 16KB tile copy (already swizzled in global)
    const char* bt = bt_base + (kc << 14);
#pragma unroll
    for (int i = 0; i < 4; ++i) {
      int chunk = i * 4 + w;
      gload_lds16(bt + chunk * 1024 + l * 16, Bs + chunk * 1024);
    }
    __syncthreads();
#pragma unroll
    for (int ks = 0; ks < 2; ++ks) {
      bf16x8 af[4], bf[4];
#pragma unroll
      for (int mt = 0; mt < 4; ++mt) {
        int m = wm * 64 + mt * 16 + lo;
        af[mt] = *(const bf16x8*)(As + m * 128 + ((ks * 64 + lg * 16) ^ ((m & 7) << 4)));
      }
#pragma unroll
      for (int nt = 0; nt < 4; ++nt) {
        int n = wn * 64 + nt * 16 + lo;
        bf[nt] = *(const bf16x8*)(Bs + n * 128 + ((ks * 64 + lg * 16) ^ ((n & 7) << 4)));
      }
#pragma unroll
      for (int mt = 0; mt < 4; ++mt)
#pragma unroll
        for (int nt = 0; nt < 4; ++nt)
          acc[mt][nt] = MFMA16(af[mt], bf[nt], acc[mt][nt]);
    }
  }

  // ---- epilogue ----
  const int mat = nb >> 2;              // 0=q 1=k 2=v
  const int h = ((nb & 3) << 1) + wn;   // head of this wave's 64 cols
  const int win = mb * 2 + wm;          // window of this wave's 64 rows
  const size_t hb = ((size_t)win * 8 + h) * 4096;

  if (mat != 1) {
    const float* bsrc = (mat == 0) ? q_bias : v_bias;
    float bias[4];
#pragma unroll
    for (int nt = 0; nt < 4; ++nt) bias[nt] = bsrc[h * 64 + nt * 16 + lo];
#pragma unroll
    for (int mt = 0; mt < 4; ++mt)
#pragma unroll
      for (int nt = 0; nt < 4; ++nt)
#pragma unroll
        for (int r = 0; r < 4; ++r) acc[mt][nt][r] += bias[nt];
  }

  if (mat < 2) {
    bf16* dst = (bf16*)(ws + (mat == 0 ? OFF_QHAT : OFF_KHAT)) + hb;
#pragma unroll
    for (int mt = 0; mt < 4; ++mt) {
#pragma unroll
      for (int r = 0; r < 4; ++r) {
        float ss = acc[mt][0][r] * acc[mt][0][r] + acc[mt][1][r] * acc[mt][1][r] +
                   acc[mt][2][r] * acc[mt][2][r] + acc[mt][3][r] * acc[mt][3][r];
#pragma unroll
        for (int s = 1; s < 16; s <<= 1) ss += __shfl_xor(ss, s, 64);
        float rinv = 1.0f / fmaxf(sqrtf(ss), 1e-12f);
        int tok = mt * 16 + lg * 4 + r;
#pragma unroll
        for (int nt = 0; nt < 4; ++nt)
          dst[tok * 64 + nt * 16 + lo] = (bf16)(acc[mt][nt][r] * rinv);
      }
    }
  } else {
    bf16* dst = (bf16*)(ws + OFF_VT) + hb;   // [d][tok]
#pragma unroll
    for (int mt = 0; mt < 4; ++mt) {
#pragma unroll
      for (int nt = 0; nt < 4; ++nt) {
        ushort4 o;
        o.x = f2bf_bits(acc[mt][nt][0]); o.y = f2bf_bits(acc[mt][nt][1]);
        o.z = f2bf_bits(acc[mt][nt][2]); o.w = f2bf_bits(acc[mt][nt][3]);
        int d = nt * 16 + lo, tok0 = mt * 16 + lg * 4;
        *(ushort4*)(dst + d * 64 + tok0) = o;
      }
    }
  }
}

// ---------------------------------------------------------------------------
// K3: attention. 1024 blocks x 4 waves; wave w handles heads 2w, 2w+1.
// Waves independent (no barriers after cpb preload). P transposed through
// per-wave swizzled LDS. attn written in pre-swizzled proj-A-tile layout.
// ---------------------------------------------------------------------------
__launch_bounds__(256)
__global__ void attn_kernel(const float* __restrict__ mask,
                            const float* __restrict__ logit_scale,
                            char* __restrict__ ws) {
  __shared__ float cpbs[1800];
  __shared__ __align__(16) char psb[4][8192];
  const int tid = threadIdx.x;
  const int w = tid >> 6, l = tid & 63, lg = l >> 4, lo = l & 15;
  const int b = blockIdx.x;
  const int widx = b & 63;

  const float* cpb_small = (const float*)(ws + OFF_CPB);
  for (int i = tid; i < 1800; i += 256) cpbs[i] = cpb_small[i];
  __syncthreads();

  const float* mrow = mask + widx * 4096;
  char* pw = psb[w];

#pragma unroll
  for (int hh = 0; hh < 2; ++hh) {
    const int h = w * 2 + hh;
    const size_t hb = ((size_t)b * 8 + h) * 4096;
    const bf16* qh = (const bf16*)(ws + OFF_QHAT) + hb;
    const bf16* kh = (const bf16*)(ws + OFF_KHAT) + hb;
    const bf16* vh = (const bf16*)(ws + OFF_VT) + hb;
    const float scale = __expf(fminf(logit_scale[h], 4.605170185988091f));

    // S = qhat @ khat^T
    f32x4 sacc[4][4];
#pragma unroll
    for (int mt = 0; mt < 4; ++mt)
#pragma unroll
      for (int nt = 0; nt < 4; ++nt) { f32x4 z = {0.f, 0.f, 0.f, 0.f}; sacc[mt][nt] = z; }
#pragma unroll
    for (int ks = 0; ks < 2; ++ks) {
      bf16x8 a4[4], b4[4];
#pragma unroll
      for (int mt = 0; mt < 4; ++mt)
        a4[mt] = *(const bf16x8*)(qh + (mt * 16 + lo) * 64 + ks * 32 + lg * 8);
#pragma unroll
      for (int nt = 0; nt < 4; ++nt)
        b4[nt] = *(const bf16x8*)(kh + (nt * 16 + lo) * 64 + ks * 32 + lg * 8);
#pragma unroll
      for (int mt = 0; mt < 4; ++mt)
#pragma unroll
        for (int nt = 0; nt < 4; ++nt)
          sacc[mt][nt] = MFMA16(a4[mt], b4[nt], sacc[mt][nt]);
    }

    // softmax (fp32) + write P bf16 to swizzled per-wave LDS
    float invl[4][4];
#pragma unroll
    for (int mt = 0; mt < 4; ++mt) {
#pragma unroll
      for (int r = 0; r < 4; ++r) {
        int row = mt * 16 + lg * 4 + r;
        float sv[4];
#pragma unroll
        for (int nt = 0; nt < 4; ++nt) {
          int col = nt * 16 + lo;
          int idx = ((row >> 3) - (col >> 3) + 7) * 15 + (row & 7) - (col & 7) + 7;
          sv[nt] = fmaf(sacc[mt][nt][r], scale, cpbs[idx * 8 + h] + mrow[row * 64 + col]);
        }
        float mr = fmaxf(fmaxf(sv[0], sv[1]), fmaxf(sv[2], sv[3]));
#pragma unroll
        for (int s = 1; s < 16; s <<= 1) mr = fmaxf(mr, __shfl_xor(mr, s, 64));
        float ls = 0.f;
#pragma unroll
        for (int nt = 0; nt < 4; ++nt) { sv[nt] = __expf(sv[nt] - mr); ls += sv[nt]; }
#pragma unroll
        for (int s = 1; s < 16; s <<= 1) ls += __shfl_xor(ls, s, 64);
        invl[mt][r] = 1.0f / ls;
#pragma unroll
        for (int nt = 0; nt < 4; ++nt)
          *(bf16*)(pw + row * 128 + (((nt * 16 + lo) * 2) ^ ((row & 7) << 4))) = (bf16)sv[nt];
      }
    }
    asm volatile("" ::: "memory");   // keep ds_write before ds_read at IR level

    // O = P @ V  (B-operand = vT rows)
    f32x4 oacc[4][4];
#pragma unroll
    for (int mt = 0; mt < 4; ++mt)
#pragma unroll
      for (int nt = 0; nt < 4; ++nt) { f32x4 z = {0.f, 0.f, 0.f, 0.f}; oacc[mt][nt] = z; }
#pragma unroll
    for (int ks = 0; ks < 2; ++ks) {
      bf16x8 pa[4], b4[4];
#pragma unroll
      for (int mt = 0; mt < 4; ++mt) {
        int m = mt * 16 + lo;
        pa[mt] = *(const bf16x8*)(pw + m * 128 + ((ks * 64 + lg * 16) ^ ((m & 7) << 4)));
      }
#pragma unroll
      for (int nt = 0; nt < 4; ++nt)
        b4[nt] = *(const bf16x8*)(vh + (nt * 16 + lo) * 64 + ks * 32 + lg * 8);
#pragma unroll
      for (int mt = 0; mt < 4; ++mt)
#pragma unroll
        for (int nt = 0; nt < 4; ++nt)
          oacc[mt][nt] = MFMA16(pa[mt], b4[nt], oacc[mt][nt]);
    }

    // store attn in pre-swizzled proj-A-tile layout: tile (b>>1, kc=h)
    char* at = ws + OFF_ATTN + ((size_t)((b >> 1) * 8 + h) << 14);
#pragma unroll
    for (int mt = 0; mt < 4; ++mt) {
#pragma unroll
      for (int r = 0; r < 4; ++r) {
        int rt = (b & 1) * 64 + mt * 16 + lg * 4 + r;
#pragma unroll
        for (int nt = 0; nt < 4; ++nt) {
          int d = nt * 16 + lo;
          *(bf16*)(at + rt * 128 + ((d * 2) ^ ((rt & 7) << 4))) =
              (bf16)(oacc[mt][nt][r] * invl[mt][r]);
        }
      }
    }
    asm volatile("" ::: "memory");   // order psb reuse across heads
  }
}

// ---------------------------------------------------------------------------
// K4: proj GEMM. out = attn(bf16 tiles) @ proj_w^T(bf16 tiles) + proj_b.
// Both operands via global_load_lds (pre-swizzled), conflict-free ds_read.
// ---------------------------------------------------------------------------
__launch_bounds__(256)
__global__ void proj_kernel(const float* __restrict__ proj_b,
                            float* __restrict__ out,
                            const char* __restrict__ ws) {
  __shared__ __align__(16) char As[16384];
  __shared__ __align__(16) char Bs[16384];
  const int tid = threadIdx.x;
  const int w = tid >> 6, l = tid & 63, lg = l >> 4, lo = l & 15;
  const int wm = w >> 1, wn = w & 1;
  const int bid = blockIdx.x;
  const int wg = (bid & 7) * 256 + (bid >> 3);   // 2048 % 8 == 0
  const int mb = wg >> 2, nbp = wg & 3;

  const char* at_base = ws + OFF_ATTN + ((size_t)mb * 8 << 14);
  const char* bt_base = ws + OFF_PROJWT + (unsigned)(nbp * 8 << 14);

  f32x4 acc[4][4];
#pragma unroll
  for (int mt = 0; mt < 4; ++mt)
#pragma unroll
    for (int nt = 0; nt < 4; ++nt) { f32x4 z = {0.f, 0.f, 0.f, 0.f}; acc[mt][nt] = z; }

#pragma unroll 1
  for (int kc = 0; kc < 8; ++kc) {
    __syncthreads();
    const char* at = at_base + (kc << 14);
    const char* bt = bt_base + (kc << 14);
#pragma unroll
    for (int i = 0; i < 4; ++i) {
      int chunk = i * 4 + w;
      gload_lds16(at + chunk * 1024 + l * 16, As + chunk * 1024);
      gload_lds16(bt + chunk * 1024 + l * 16, Bs + chunk * 1024);
    }
    __syncthreads();
#pragma unroll
    for (int ks = 0; ks < 2; ++ks) {
      bf16x8 af[4], bf[4];
#pragma unroll
      for (int mt = 0; mt < 4; ++mt) {
        int m = wm * 64 + mt * 16 + lo;
        af[mt] = *(const bf16x8*)(As + m * 128 + ((ks * 64 + lg * 16) ^ ((m & 7) << 4)));
      }
#pragma unroll
      for (int nt = 0; nt < 4; ++nt) {
        int n = wn * 64 + nt * 16 + lo;
        bf[nt] = *(const bf16x8*)(Bs + n * 128 + ((ks * 64 + lg * 16) ^ ((n & 7) << 4)));
      }
#pragma unroll
      for (int mt = 0; mt < 4; ++mt)
#pragma unroll
        for (int nt = 0; nt < 4; ++nt)
          acc[mt][nt] = MFMA16(af[mt], bf[nt], acc[mt][nt]);
    }
  }
#pragma unroll
  for (int nt = 0; nt < 4; ++nt) {
    int col = nbp * 128 + wn * 64 + nt * 16 + lo;
    float pb = proj_b[col];
#pragma unroll
    for (int mt = 0; mt < 4; ++mt) {
#pragma unroll
      for (int r = 0; r < 4; ++r) {
        int row = mb * 128 + wm * 64 + mt * 16 + lg * 4 + r;
        out[(size_t)row * 512 + col] = acc[mt][nt][r] + pb;
      }
    }
  }
}

// ---------------------------------------------------------------------------
extern "C" void kernel_launch(void* const* d_in, const int* in_sizes, int n_in,
                              void* d_out, int out_size, void* d_ws, size_t ws_size,
                              hipStream_t stream) {
  const float* x      = (const float*)d_in[0];
  const float* mask   = (const float*)d_in[1];
  const float* qkvw   = (const float*)d_in[2];
  const float* q_bias = (const float*)d_in[3];
  const float* v_bias = (const float*)d_in[4];
  const float* ls     = (const float*)d_in[5];
  const float* cpb_w1 = (const float*)d_in[6];
  const float* cpb_b1 = (const float*)d_in[7];
  const float* cpb_w2 = (const float*)d_in[8];
  const float* proj_w = (const float*)d_in[9];
  const float* proj_b = (const float*)d_in[10];
  float* out = (float*)d_out;
  char* ws = (char*)d_ws;

  hipLaunchKernelGGL(wconv_kernel, dim3(256), dim3(256), 0, stream, qkvw, proj_w, ws);
  hipLaunchKernelGGL(cpb_kernel, dim3(225), dim3(256), 0, stream,
                     cpb_w1, cpb_b1, cpb_w2, (float*)(ws + OFF_CPB));
  hipLaunchKernelGGL(qkv_gemm, dim3(6144), dim3(256), 0, stream, x, q_bias, v_bias, ws);
  hipLaunchKernelGGL(attn_kernel, dim3(1024), dim3(256), 0, stream, mask, ls, ws);
  hipLaunchKernelGGL(proj_kernel, dim3(2048), dim3(256), 0, stream, proj_b, out, ws);
}

// Round 4
// 574.535 us; speedup vs baseline: 3.1759x; 1.0032x over previous
//
#include <hip/hip_runtime.h>

// ---------------------------------------------------------------------------
// Swin-V2 window attention, MI355X (gfx950).
// B=1024 windows, N=64 tokens, C=512, NH=8 heads, HD=64.
//
//   K0 wconv : qkv_w/proj_w f32 -> bf16 PRE-SWIZZLED [nb][kc][128][64] tiles
//   K0b xconv: x f32 -> bf16 PRE-SWIZZLED A-tiles [mb][kc][128][64] (aliases
//              the ATTN ws region -- dead until attn_kernel runs)
//   K1 cpb   : rel-pos MLP -> cpb_small[225][8] f32
//   K2 qkv   : [65536x1536] GEMM, BOTH operands via global_load_lds from
//              pre-swizzled tiles + fused bias/normalize epilogue
//              -> qhat,khat [win,h,tok,d], vT [win,h,d,tok] bf16
//   K3 attn  : per (window,head-wave): QK MFMA + fp32 softmax + PV MFMA
//              -> attn in pre-swizzled proj-A-tile layout
//   K4 proj  : [65536x512]@[512x512]^T, both operands via global_load_lds
//
// R4: qkv was VALU-bound (VALUBusy 40% vs MfmaUtil 19%) on in-loop f32->bf16
// A-staging, repeated 12x per x element (once per n-block). xconv converts
// once; qkv staging is now pure global_load_lds.
// ---------------------------------------------------------------------------

typedef __bf16 bf16;
typedef bf16  bf16x8 __attribute__((ext_vector_type(8)));
typedef float f32x4  __attribute__((ext_vector_type(4)));

#define MFMA16(a, b, c) __builtin_amdgcn_mfma_f32_16x16x32_bf16((a), (b), (c), 0, 0, 0)

__device__ __forceinline__ unsigned short f2bf_bits(float f) {
  return __builtin_bit_cast(unsigned short, (bf16)f);
}

__device__ __forceinline__ void gload_lds16(const void* g, void* l) {
  __builtin_amdgcn_global_load_lds(
      (const __attribute__((address_space(1))) void*)g,
      (__attribute__((address_space(3))) void*)l, 16, 0, 0);
}

// ws layout (bytes)
#define OFF_CPB     0u           // 225*8*4 = 7200, pad to 8192
#define OFF_QKVWT   8192u        // 12*8*16384 = 1572864
#define OFF_PROJWT  1581056u     // 4*8*16384  = 524288
#define OFF_QHAT    2105344u     // 67108864
#define OFF_KHAT    69214208u    // 67108864
#define OFF_VT      136323072u   // 67108864
#define OFF_ATTN    203431936u   // 512*8*16384 = 67108864  (total ~258 MB)
#define OFF_XT      OFF_ATTN     // aliased: xt dead before attn writes

// ---------------------------------------------------------------------------
// K0: weights f32 -> bf16 pre-swizzled tiles [nb][kc][n 128][k 64],
// byte(n,k) = n*128 + ((k*2) ^ ((n&7)<<4)).
// ---------------------------------------------------------------------------
__global__ void wconv_kernel(const float* __restrict__ qkvw,
                             const float* __restrict__ projw,
                             char* __restrict__ ws) {
  int i = blockIdx.x * 256 + threadIdx.x;
#pragma unroll
  for (int it = 0; it < 4; ++it) {
    int idx = i + it * 65536;  // ushort4 index; 262144 total
    const float* src;
    unsigned base;
    int row, c4;
    if (idx < 196608) {               // qkvw [1536][512]
      row = idx >> 7; c4 = idx & 127;
      src = qkvw + row * 512 + c4 * 4;
      base = OFF_QKVWT + (unsigned)(((row >> 7) * 8 + (c4 >> 4)) << 14);
    } else {                          // projw [512][512]
      int j = idx - 196608;
      row = j >> 7; c4 = j & 127;
      src = projw + row * 512 + c4 * 4;
      base = OFF_PROJWT + (unsigned)(((row >> 7) * 8 + (c4 >> 4)) << 14);
    }
    int n = row & 127;
    int kb = (c4 & 15) * 8;           // byte offset of k within 128B row
    float4 v = *(const float4*)src;
    ushort4 o;
    o.x = f2bf_bits(v.x); o.y = f2bf_bits(v.y);
    o.z = f2bf_bits(v.z); o.w = f2bf_bits(v.w);
    *(ushort4*)(ws + base + n * 128 + (kb ^ ((n & 7) << 4))) = o;
  }
}

// ---------------------------------------------------------------------------
// K0b: x f32 -> bf16 pre-swizzled A-tiles [mb 512][kc 8][row 128][k 64].
// 8192 blocks x 256 threads x 4 iters = 8388608 float4.
// ---------------------------------------------------------------------------
__global__ void xconv_kernel(const float* __restrict__ x, char* __restrict__ ws) {
  int i = blockIdx.x * 1024 + threadIdx.x;
#pragma unroll
  for (int it = 0; it < 4; ++it) {
    int idx = i + it * 256;
    int row = idx >> 7, c4 = idx & 127;
    float4 v = *((const float4*)x + idx);
    ushort4 o;
    o.x = f2bf_bits(v.x); o.y = f2bf_bits(v.y);
    o.z = f2bf_bits(v.z); o.w = f2bf_bits(v.w);
    int n = row & 127;
    int kb = (c4 & 15) * 8;
    size_t base = OFF_XT + ((size_t)((row >> 7) * 8 + (c4 >> 4)) << 14);
    *(ushort4*)(ws + base + n * 128 + (kb ^ ((n & 7) << 4))) = o;
  }
}

// ---------------------------------------------------------------------------
// K1: CPB MLP -> cpb_small[225][8].  225 blocks, 256 threads reduce over j.
// ---------------------------------------------------------------------------
__global__ void cpb_kernel(const float* __restrict__ w1, const float* __restrict__ b1,
                           const float* __restrict__ w2, float* __restrict__ cpb_small) {
  const int t = blockIdx.x;     // rel-pos index 0..224
  const int tid = threadIdx.x;
  const int a = t / 15, bb = t % 15;
  const float rh = (float)(a - 7) * (8.0f / 7.0f);
  const float rw = (float)(bb - 7) * (8.0f / 7.0f);
  const float inv_log2_9 = 0.3154648767971186f;
  float sh = (rh > 0.f) ? 1.f : ((rh < 0.f) ? -1.f : 0.f);
  float sw = (rw > 0.f) ? 1.f : ((rw < 0.f) ? -1.f : 0.f);
  float c0 = sh * log2f(fabsf(rh) + 1.0f) * inv_log2_9;
  float c1 = sw * log2f(fabsf(rw) + 1.0f) * inv_log2_9;
  float acc[8] = {0, 0, 0, 0, 0, 0, 0, 0};
  for (int j = tid; j < 512; j += 256) {
    float hv = fmaf(c0, w1[2 * j], fmaf(c1, w1[2 * j + 1], b1[j]));
    hv = fmaxf(hv, 0.0f);
#pragma unroll
    for (int hh = 0; hh < 8; ++hh) acc[hh] = fmaf(hv, w2[hh * 512 + j], acc[hh]);
  }
#pragma unroll
  for (int hh = 0; hh < 8; ++hh)
#pragma unroll
    for (int s = 1; s < 64; s <<= 1) acc[hh] += __shfl_xor(acc[hh], s, 64);
  __shared__ float wsum[4][8];
  if ((tid & 63) == 0) {
#pragma unroll
    for (int hh = 0; hh < 8; ++hh) wsum[tid >> 6][hh] = acc[hh];
  }
  __syncthreads();
  if (tid < 8) {
    float s = wsum[0][tid] + wsum[1][tid] + wsum[2][tid] + wsum[3][tid];
    cpb_small[t * 8 + tid] = 16.0f / (1.0f + expf(-s));
  }
}

// ---------------------------------------------------------------------------
// K2: QKV GEMM [65536 x 1536], K=512.  128x128 tile, BK=64, 4 waves 2x2.
// A and B both via global_load_lds from pre-swizzled tiles.
// Epilogue: bias + per-row q/k normalize + scatter stores.
// ---------------------------------------------------------------------------
__launch_bounds__(256)
__global__ void qkv_gemm(const float* __restrict__ q_bias,
                         const float* __restrict__ v_bias,
                         char* __restrict__ ws) {
  __shared__ __align__(16) char As[16384];
  __shared__ __align__(16) char Bs[16384];
  const int tid = threadIdx.x;
  const int w = tid >> 6, l = tid & 63, lg = l >> 4, lo = l & 15;
  const int wm = w >> 1, wn = w & 1;
  const int bid = blockIdx.x;
  const int wg = (bid & 7) * 768 + (bid >> 3);   // XCD-contiguous (6144 % 8 == 0)
  const int mb = wg / 12, nb = wg % 12;

  const char* at_base = ws + OFF_XT + ((size_t)mb * 8 << 14);
  const char* bt_base = ws + OFF_QKVWT + (unsigned)(nb * 8 << 14);

  f32x4 acc[4][4];
#pragma unroll
  for (int mt = 0; mt < 4; ++mt)
#pragma unroll
    for (int nt = 0; nt < 4; ++nt) { f32x4 z = {0.f, 0.f, 0.f, 0.f}; acc[mt][nt] = z; }

#pragma unroll 1
  for (int kc = 0; kc < 8; ++kc) {
    __syncthreads();
    const char* at = at_base + (kc << 14);
    const char* bt = bt_base + (kc << 14);
#pragma unroll
    for (int i = 0; i < 4; ++i) {
      int chunk = i * 4 + w;
      gload_lds16(at + chunk * 1024 + l * 16, As + chunk * 1024);
      gload_lds16(bt + chunk * 1024 + l * 16, Bs + chunk * 1024);
    }
    __syncthreads();
#pragma unroll
    for (int ks = 0; ks < 2; ++ks) {
      bf16x8 af[4], bf[4];
#pragma unroll
      for (int mt = 0; mt < 4; ++mt) {
        int m = wm * 64 + mt * 16 + lo;
        af[mt] = *(const bf16x8*)(As + m * 128 + ((ks * 64 + lg * 16) ^ ((m & 7) << 4)));
      }
#pragma unroll
      for (int nt = 0; nt < 4; ++nt) {
        int n = wn * 64 + nt * 16 + lo;
        bf[nt] = *(const bf16x8*)(Bs + n * 128 + ((ks * 64 + lg * 16) ^ ((n & 7) << 4)));
      }
#pragma unroll
      for (int mt = 0; mt < 4; ++mt)
#pragma unroll
        for (int nt = 0; nt < 4; ++nt)
          acc[mt][nt] = MFMA16(af[mt], bf[nt], acc[mt][nt]);
    }
  }

  // ---- epilogue ----
  const int mat = nb >> 2;              // 0=q 1=k 2=v
  const int h = ((nb & 3) << 1) + wn;   // head of this wave's 64 cols
  const int win = mb * 2 + wm;          // window of this wave's 64 rows
  const size_t hb = ((size_t)win * 8 + h) * 4096;

  if (mat != 1) {
    const float* bsrc = (mat == 0) ? q_bias : v_bias;
    float bias[4];
#pragma unroll
    for (int nt = 0; nt < 4; ++nt) bias[nt] = bsrc[h * 64 + nt * 16 + lo];
#pragma unroll
    for (int mt = 0; mt < 4; ++mt)
#pragma unroll
      for (int nt = 0; nt < 4; ++nt)
#pragma unroll
        for (int r = 0; r < 4; ++r) acc[mt][nt][r] += bias[nt];
  }

  if (mat < 2) {
    bf16* dst = (bf16*)(ws + (mat == 0 ? OFF_QHAT : OFF_KHAT)) + hb;
#pragma unroll
    for (int mt = 0; mt < 4; ++mt) {
#pragma unroll
      for (int r = 0; r < 4; ++r) {
        float ss = acc[mt][0][r] * acc[mt][0][r] + acc[mt][1][r] * acc[mt][1][r] +
                   acc[mt][2][r] * acc[mt][2][r] + acc[mt][3][r] * acc[mt][3][r];
#pragma unroll
        for (int s = 1; s < 16; s <<= 1) ss += __shfl_xor(ss, s, 64);
        float rinv = 1.0f / fmaxf(sqrtf(ss), 1e-12f);
        int tok = mt * 16 + lg * 4 + r;
#pragma unroll
        for (int nt = 0; nt < 4; ++nt)
          dst[tok * 64 + nt * 16 + lo] = (bf16)(acc[mt][nt][r] * rinv);
      }
    }
  } else {
    bf16* dst = (bf16*)(ws + OFF_VT) + hb;   // [d][tok]
#pragma unroll
    for (int mt = 0; mt < 4; ++mt) {
#pragma unroll
      for (int nt = 0; nt < 4; ++nt) {
        ushort4 o;
        o.x = f2bf_bits(acc[mt][nt][0]); o.y = f2bf_bits(acc[mt][nt][1]);
        o.z = f2bf_bits(acc[mt][nt][2]); o.w = f2bf_bits(acc[mt][nt][3]);
        int d = nt * 16 + lo, tok0 = mt * 16 + lg * 4;
        *(ushort4*)(dst + d * 64 + tok0) = o;
      }
    }
  }
}

// ---------------------------------------------------------------------------
// K3: attention. 1024 blocks x 4 waves; wave w handles heads 2w, 2w+1.
// Waves independent (no barriers after cpb preload). P transposed through
// per-wave swizzled LDS. attn written in pre-swizzled proj-A-tile layout.
// ---------------------------------------------------------------------------
__launch_bounds__(256)
__global__ void attn_kernel(const float* __restrict__ mask,
                            const float* __restrict__ logit_scale,
                            char* __restrict__ ws) {
  __shared__ float cpbs[1800];
  __shared__ __align__(16) char psb[4][8192];
  const int tid = threadIdx.x;
  const int w = tid >> 6, l = tid & 63, lg = l >> 4, lo = l & 15;
  const int b = blockIdx.x;
  const int widx = b & 63;

  const float* cpb_small = (const float*)(ws + OFF_CPB);
  for (int i = tid; i < 1800; i += 256) cpbs[i] = cpb_small[i];
  __syncthreads();

  const float* mrow = mask + widx * 4096;
  char* pw = psb[w];

#pragma unroll
  for (int hh = 0; hh < 2; ++hh) {
    const int h = w * 2 + hh;
    const size_t hb = ((size_t)b * 8 + h) * 4096;
    const bf16* qh = (const bf16*)(ws + OFF_QHAT) + hb;
    const bf16* kh = (const bf16*)(ws + OFF_KHAT) + hb;
    const bf16* vh = (const bf16*)(ws + OFF_VT) + hb;
    const float scale = __expf(fminf(logit_scale[h], 4.605170185988091f));

    // S = qhat @ khat^T
    f32x4 sacc[4][4];
#pragma unroll
    for (int mt = 0; mt < 4; ++mt)
#pragma unroll
      for (int nt = 0; nt < 4; ++nt) { f32x4 z = {0.f, 0.f, 0.f, 0.f}; sacc[mt][nt] = z; }
#pragma unroll
    for (int ks = 0; ks < 2; ++ks) {
      bf16x8 a4[4], b4[4];
#pragma unroll
      for (int mt = 0; mt < 4; ++mt)
        a4[mt] = *(const bf16x8*)(qh + (mt * 16 + lo) * 64 + ks * 32 + lg * 8);
#pragma unroll
      for (int nt = 0; nt < 4; ++nt)
        b4[nt] = *(const bf16x8*)(kh + (nt * 16 + lo) * 64 + ks * 32 + lg * 8);
#pragma unroll
      for (int mt = 0; mt < 4; ++mt)
#pragma unroll
        for (int nt = 0; nt < 4; ++nt)
          sacc[mt][nt] = MFMA16(a4[mt], b4[nt], sacc[mt][nt]);
    }

    // softmax (fp32) + write P bf16 to swizzled per-wave LDS
    float invl[4][4];
#pragma unroll
    for (int mt = 0; mt < 4; ++mt) {
#pragma unroll
      for (int r = 0; r < 4; ++r) {
        int row = mt * 16 + lg * 4 + r;
        float sv[4];
#pragma unroll
        for (int nt = 0; nt < 4; ++nt) {
          int col = nt * 16 + lo;
          int idx = ((row >> 3) - (col >> 3) + 7) * 15 + (row & 7) - (col & 7) + 7;
          sv[nt] = fmaf(sacc[mt][nt][r], scale, cpbs[idx * 8 + h] + mrow[row * 64 + col]);
        }
        float mr = fmaxf(fmaxf(sv[0], sv[1]), fmaxf(sv[2], sv[3]));
#pragma unroll
        for (int s = 1; s < 16; s <<= 1) mr = fmaxf(mr, __shfl_xor(mr, s, 64));
        float ls = 0.f;
#pragma unroll
        for (int nt = 0; nt < 4; ++nt) { sv[nt] = __expf(sv[nt] - mr); ls += sv[nt]; }
#pragma unroll
        for (int s = 1; s < 16; s <<= 1) ls += __shfl_xor(ls, s, 64);
        invl[mt][r] = 1.0f / ls;
#pragma unroll
        for (int nt = 0; nt < 4; ++nt)
          *(bf16*)(pw + row * 128 + (((nt * 16 + lo) * 2) ^ ((row & 7) << 4))) = (bf16)sv[nt];
      }
    }
    asm volatile("" ::: "memory");   // keep ds_write before ds_read at IR level

    // O = P @ V  (B-operand = vT rows)
    f32x4 oacc[4][4];
#pragma unroll
    for (int mt = 0; mt < 4; ++mt)
#pragma unroll
      for (int nt = 0; nt < 4; ++nt) { f32x4 z = {0.f, 0.f, 0.f, 0.f}; oacc[mt][nt] = z; }
#pragma unroll
    for (int ks = 0; ks < 2; ++ks) {
      bf16x8 pa[4], b4[4];
#pragma unroll
      for (int mt = 0; mt < 4; ++mt) {
        int m = mt * 16 + lo;
        pa[mt] = *(const bf16x8*)(pw + m * 128 + ((ks * 64 + lg * 16) ^ ((m & 7) << 4)));
      }
#pragma unroll
      for (int nt = 0; nt < 4; ++nt)
        b4[nt] = *(const bf16x8*)(vh + (nt * 16 + lo) * 64 + ks * 32 + lg * 8);
#pragma unroll
      for (int mt = 0; mt < 4; ++mt)
#pragma unroll
        for (int nt = 0; nt < 4; ++nt)
          oacc[mt][nt] = MFMA16(pa[mt], b4[nt], oacc[mt][nt]);
    }

    // store attn in pre-swizzled proj-A-tile layout: tile (b>>1, kc=h)
    char* at = ws + OFF_ATTN + ((size_t)((b >> 1) * 8 + h) << 14);
#pragma unroll
    for (int mt = 0; mt < 4; ++mt) {
#pragma unroll
      for (int r = 0; r < 4; ++r) {
        int rt = (b & 1) * 64 + mt * 16 + lg * 4 + r;
#pragma unroll
        for (int nt = 0; nt < 4; ++nt) {
          int d = nt * 16 + lo;
          *(bf16*)(at + rt * 128 + ((d * 2) ^ ((rt & 7) << 4))) =
              (bf16)(oacc[mt][nt][r] * invl[mt][r]);
        }
      }
    }
    asm volatile("" ::: "memory");   // order psb reuse across heads
  }
}

// ---------------------------------------------------------------------------
// K4: proj GEMM. out = attn(bf16 tiles) @ proj_w^T(bf16 tiles) + proj_b.
// Both operands via global_load_lds (pre-swizzled), conflict-free ds_read.
// ---------------------------------------------------------------------------
__launch_bounds__(256)
__global__ void proj_kernel(const float* __restrict__ proj_b,
                            float* __restrict__ out,
                            const char* __restrict__ ws) {
  __shared__ __align__(16) char As[16384];
  __shared__ __align__(16) char Bs[16384];
  const int tid = threadIdx.x;
  const int w = tid >> 6, l = tid & 63, lg = l >> 4, lo = l & 15;
  const int wm = w >> 1, wn = w & 1;
  const int bid = blockIdx.x;
  const int wg = (bid & 7) * 256 + (bid >> 3);   // 2048 % 8 == 0
  const int mb = wg >> 2, nbp = wg & 3;

  const char* at_base = ws + OFF_ATTN + ((size_t)mb * 8 << 14);
  const char* bt_base = ws + OFF_PROJWT + (unsigned)(nbp * 8 << 14);

  f32x4 acc[4][4];
#pragma unroll
  for (int mt = 0; mt < 4; ++mt)
#pragma unroll
    for (int nt = 0; nt < 4; ++nt) { f32x4 z = {0.f, 0.f, 0.f, 0.f}; acc[mt][nt] = z; }

#pragma unroll 1
  for (int kc = 0; kc < 8; ++kc) {
    __syncthreads();
    const char* at = at_base + (kc << 14);
    const char* bt = bt_base + (kc << 14);
#pragma unroll
    for (int i = 0; i < 4; ++i) {
      int chunk = i * 4 + w;
      gload_lds16(at + chunk * 1024 + l * 16, As + chunk * 1024);
      gload_lds16(bt + chunk * 1024 + l * 16, Bs + chunk * 1024);
    }
    __syncthreads();
#pragma unroll
    for (int ks = 0; ks < 2; ++ks) {
      bf16x8 af[4], bf[4];
#pragma unroll
      for (int mt = 0; mt < 4; ++mt) {
        int m = wm * 64 + mt * 16 + lo;
        af[mt] = *(const bf16x8*)(As + m * 128 + ((ks * 64 + lg * 16) ^ ((m & 7) << 4)));
      }
#pragma unroll
      for (int nt = 0; nt < 4; ++nt) {
        int n = wn * 64 + nt * 16 + lo;
        bf[nt] = *(const bf16x8*)(Bs + n * 128 + ((ks * 64 + lg * 16) ^ ((n & 7) << 4)));
      }
#pragma unroll
      for (int mt = 0; mt < 4; ++mt)
#pragma unroll
        for (int nt = 0; nt < 4; ++nt)
          acc[mt][nt] = MFMA16(af[mt], bf[nt], acc[mt][nt]);
    }
  }
#pragma unroll
  for (int nt = 0; nt < 4; ++nt) {
    int col = nbp * 128 + wn * 64 + nt * 16 + lo;
    float pb = proj_b[col];
#pragma unroll
    for (int mt = 0; mt < 4; ++mt) {
#pragma unroll
      for (int r = 0; r < 4; ++r) {
        int row = mb * 128 + wm * 64 + mt * 16 + lg * 4 + r;
        out[(size_t)row * 512 + col] = acc[mt][nt][r] + pb;
      }
    }
  }
}

// ---------------------------------------------------------------------------
extern "C" void kernel_launch(void* const* d_in, const int* in_sizes, int n_in,
                              void* d_out, int out_size, void* d_ws, size_t ws_size,
                              hipStream_t stream) {
  const float* x      = (const float*)d_in[0];
  const float* mask   = (const float*)d_in[1];
  const float* qkvw   = (const float*)d_in[2];
  const float* q_bias = (const float*)d_in[3];
  const float* v_bias = (const float*)d_in[4];
  const float* ls     = (const float*)d_in[5];
  const float* cpb_w1 = (const float*)d_in[6];
  const float* cpb_b1 = (const float*)d_in[7];
  const float* cpb_w2 = (const float*)d_in[8];
  const float* proj_w = (const float*)d_in[9];
  const float* proj_b = (const float*)d_in[10];
  float* out = (float*)d_out;
  char* ws = (char*)d_ws;

  hipLaunchKernelGGL(wconv_kernel, dim3(256), dim3(256), 0, stream, qkvw, proj_w, ws);
  hipLaunchKernelGGL(xconv_kernel, dim3(8192), dim3(256), 0, stream, x, ws);
  hipLaunchKernelGGL(cpb_kernel, dim3(225), dim3(256), 0, stream,
                     cpb_w1, cpb_b1, cpb_w2, (float*)(ws + OFF_CPB));
  hipLaunchKernelGGL(qkv_gemm, dim3(6144), dim3(256), 0, stream, q_bias, v_bias, ws);
  hipLaunchKernelGGL(attn_kernel, dim3(1024), dim3(256), 0, stream, mask, ls, ws);
  hipLaunchKernelGGL(proj_kernel, dim3(2048), dim3(256), 0, stream, proj_b, out, ws);
}

// Round 5
// 554.641 us; speedup vs baseline: 3.2898x; 1.0359x over previous
//
#include <hip/hip_runtime.h>

// ---------------------------------------------------------------------------
// Swin-V2 window attention, MI355X (gfx950).
// B=1024 windows, N=64 tokens, C=512, NH=8 heads, HD=64.
//
//   K0 wconv : qkv_w/proj_w f32 -> bf16 PRE-SWIZZLED [nb][kc][128][64] tiles
//   K0b xconv: x f32 -> bf16 PRE-SWIZZLED A-tiles (aliases ATTN region)
//   K1 cpb   : rel-pos MLP -> cpb_small[225][8] f32
//   K1b bmask: bm[widx][h][64][64] = cpb-bias + mask  (8 MB, computed once)
//   K2 qkv   : [65536x1536] GEMM via global_load_lds + fused bias/normalize
//              -> qhat,khat [win,h,tok,d], vT [win,h,d,tok] bf16
//   K3 attn  : per (window, head-wave): QK MFMA + fp32 softmax (bm-table) +
//              PV MFMA; O bounced through LDS -> 16B-coalesced tile stores
//   K4 proj  : [65536x512]@[512x512]^T via global_load_lds tiles
//
// R5: attn was instruction-bound: per-element rel-idx math + mask load moved
// to bmask (runs 512x once instead of 8192x/call); O stores now LDS-bounced
// (8 dwordx4 vs 64 scalar 2B per thread/head); no block barriers in attn.
// ---------------------------------------------------------------------------

typedef __bf16 bf16;
typedef bf16  bf16x8 __attribute__((ext_vector_type(8)));
typedef float f32x4  __attribute__((ext_vector_type(4)));

#define MFMA16(a, b, c) __builtin_amdgcn_mfma_f32_16x16x32_bf16((a), (b), (c), 0, 0, 0)

__device__ __forceinline__ unsigned short f2bf_bits(float f) {
  return __builtin_bit_cast(unsigned short, (bf16)f);
}

__device__ __forceinline__ void gload_lds16(const void* g, void* l) {
  __builtin_amdgcn_global_load_lds(
      (const __attribute__((address_space(1))) void*)g,
      (__attribute__((address_space(3))) void*)l, 16, 0, 0);
}

// ws layout (bytes)
#define OFF_CPB     0u           // 225*8*4 = 7200, pad to 8192
#define OFF_QKVWT   8192u        // 12*8*16384 = 1572864
#define OFF_PROJWT  1581056u     // 4*8*16384  = 524288
#define OFF_QHAT    2105344u     // 67108864
#define OFF_KHAT    69214208u    // 67108864
#define OFF_VT      136323072u   // 67108864
#define OFF_ATTN    203431936u   // 512*8*16384 = 67108864
#define OFF_XT      OFF_ATTN     // aliased: xt dead before attn writes
#define OFF_BM      270540800u   // 64*8*4096*4 = 8388608  (total ~266 MB)

// ---------------------------------------------------------------------------
// K0: weights f32 -> bf16 pre-swizzled tiles [nb][kc][n 128][k 64],
// byte(n,k) = n*128 + ((k*2) ^ ((n&7)<<4)).
// ---------------------------------------------------------------------------
__global__ void wconv_kernel(const float* __restrict__ qkvw,
                             const float* __restrict__ projw,
                             char* __restrict__ ws) {
  int i = blockIdx.x * 256 + threadIdx.x;
#pragma unroll
  for (int it = 0; it < 4; ++it) {
    int idx = i + it * 65536;  // ushort4 index; 262144 total
    const float* src;
    unsigned base;
    int row, c4;
    if (idx < 196608) {               // qkvw [1536][512]
      row = idx >> 7; c4 = idx & 127;
      src = qkvw + row * 512 + c4 * 4;
      base = OFF_QKVWT + (unsigned)(((row >> 7) * 8 + (c4 >> 4)) << 14);
    } else {                          // projw [512][512]
      int j = idx - 196608;
      row = j >> 7; c4 = j & 127;
      src = projw + row * 512 + c4 * 4;
      base = OFF_PROJWT + (unsigned)(((row >> 7) * 8 + (c4 >> 4)) << 14);
    }
    int n = row & 127;
    int kb = (c4 & 15) * 8;           // byte offset of k within 128B row
    float4 v = *(const float4*)src;
    ushort4 o;
    o.x = f2bf_bits(v.x); o.y = f2bf_bits(v.y);
    o.z = f2bf_bits(v.z); o.w = f2bf_bits(v.w);
    *(ushort4*)(ws + base + n * 128 + (kb ^ ((n & 7) << 4))) = o;
  }
}

// ---------------------------------------------------------------------------
// K0b: x f32 -> bf16 pre-swizzled A-tiles [mb 512][kc 8][row 128][k 64].
// ---------------------------------------------------------------------------
__global__ void xconv_kernel(const float* __restrict__ x, char* __restrict__ ws) {
  int i = blockIdx.x * 1024 + threadIdx.x;
#pragma unroll
  for (int it = 0; it < 4; ++it) {
    int idx = i + it * 256;
    int row = idx >> 7, c4 = idx & 127;
    float4 v = *((const float4*)x + idx);
    ushort4 o;
    o.x = f2bf_bits(v.x); o.y = f2bf_bits(v.y);
    o.z = f2bf_bits(v.z); o.w = f2bf_bits(v.w);
    int n = row & 127;
    int kb = (c4 & 15) * 8;
    size_t base = OFF_XT + ((size_t)((row >> 7) * 8 + (c4 >> 4)) << 14);
    *(ushort4*)(ws + base + n * 128 + (kb ^ ((n & 7) << 4))) = o;
  }
}

// ---------------------------------------------------------------------------
// K1: CPB MLP -> cpb_small[225][8].  225 blocks, 256 threads reduce over j.
// ---------------------------------------------------------------------------
__global__ void cpb_kernel(const float* __restrict__ w1, const float* __restrict__ b1,
                           const float* __restrict__ w2, float* __restrict__ cpb_small) {
  const int t = blockIdx.x;     // rel-pos index 0..224
  const int tid = threadIdx.x;
  const int a = t / 15, bb = t % 15;
  const float rh = (float)(a - 7) * (8.0f / 7.0f);
  const float rw = (float)(bb - 7) * (8.0f / 7.0f);
  const float inv_log2_9 = 0.3154648767971186f;
  float sh = (rh > 0.f) ? 1.f : ((rh < 0.f) ? -1.f : 0.f);
  float sw = (rw > 0.f) ? 1.f : ((rw < 0.f) ? -1.f : 0.f);
  float c0 = sh * log2f(fabsf(rh) + 1.0f) * inv_log2_9;
  float c1 = sw * log2f(fabsf(rw) + 1.0f) * inv_log2_9;
  float acc[8] = {0, 0, 0, 0, 0, 0, 0, 0};
  for (int j = tid; j < 512; j += 256) {
    float hv = fmaf(c0, w1[2 * j], fmaf(c1, w1[2 * j + 1], b1[j]));
    hv = fmaxf(hv, 0.0f);
#pragma unroll
    for (int hh = 0; hh < 8; ++hh) acc[hh] = fmaf(hv, w2[hh * 512 + j], acc[hh]);
  }
#pragma unroll
  for (int hh = 0; hh < 8; ++hh)
#pragma unroll
    for (int s = 1; s < 64; s <<= 1) acc[hh] += __shfl_xor(acc[hh], s, 64);
  __shared__ float wsum[4][8];
  if ((tid & 63) == 0) {
#pragma unroll
    for (int hh = 0; hh < 8; ++hh) wsum[tid >> 6][hh] = acc[hh];
  }
  __syncthreads();
  if (tid < 8) {
    float s = wsum[0][tid] + wsum[1][tid] + wsum[2][tid] + wsum[3][tid];
    cpb_small[t * 8 + tid] = 16.0f / (1.0f + expf(-s));
  }
}

// ---------------------------------------------------------------------------
// K1b: bm[widx][h][row][col] = cpb_small[relidx(row,col)][h] + mask[widx][row][col]
// 512 blocks (widx*8+h) x 256 threads.
// ---------------------------------------------------------------------------
__global__ void bmask_kernel(const float* __restrict__ mask,
                             const float* __restrict__ cpb_small,
                             float* __restrict__ bm) {
  const int blk = blockIdx.x;          // widx*8 + h
  const int widx = blk >> 3, h = blk & 7;
  const float* mrow = mask + widx * 4096;
  float* dst = bm + (size_t)blk * 4096;
#pragma unroll
  for (int it = 0; it < 16; ++it) {
    int e = it * 256 + threadIdx.x;
    int row = e >> 6, col = e & 63;
    int idx = ((row >> 3) - (col >> 3) + 7) * 15 + ((row & 7) - (col & 7) + 7);
    dst[e] = cpb_small[idx * 8 + h] + mrow[e];
  }
}

// ---------------------------------------------------------------------------
// K2: QKV GEMM [65536 x 1536], K=512.  128x128 tile, BK=64, 4 waves 2x2.
// A and B both via global_load_lds from pre-swizzled tiles.
// Epilogue: bias + per-row q/k normalize + scatter stores.
// ---------------------------------------------------------------------------
__launch_bounds__(256)
__global__ void qkv_gemm(const float* __restrict__ q_bias,
                         const float* __restrict__ v_bias,
                         char* __restrict__ ws) {
  __shared__ __align__(16) char As[16384];
  __shared__ __align__(16) char Bs[16384];
  const int tid = threadIdx.x;
  const int w = tid >> 6, l = tid & 63, lg = l >> 4, lo = l & 15;
  const int wm = w >> 1, wn = w & 1;
  const int bid = blockIdx.x;
  const int wg = (bid & 7) * 768 + (bid >> 3);   // XCD-contiguous (6144 % 8 == 0)
  const int mb = wg / 12, nb = wg % 12;

  const char* at_base = ws + OFF_XT + ((size_t)mb * 8 << 14);
  const char* bt_base = ws + OFF_QKVWT + (unsigned)(nb * 8 << 14);

  f32x4 acc[4][4];
#pragma unroll
  for (int mt = 0; mt < 4; ++mt)
#pragma unroll
    for (int nt = 0; nt < 4; ++nt) { f32x4 z = {0.f, 0.f, 0.f, 0.f}; acc[mt][nt] = z; }

#pragma unroll 1
  for (int kc = 0; kc < 8; ++kc) {
    __syncthreads();
    const char* at = at_base + (kc << 14);
    const char* bt = bt_base + (kc << 14);
#pragma unroll
    for (int i = 0; i < 4; ++i) {
      int chunk = i * 4 + w;
      gload_lds16(at + chunk * 1024 + l * 16, As + chunk * 1024);
      gload_lds16(bt + chunk * 1024 + l * 16, Bs + chunk * 1024);
    }
    __syncthreads();
#pragma unroll
    for (int ks = 0; ks < 2; ++ks) {
      bf16x8 af[4], bf[4];
#pragma unroll
      for (int mt = 0; mt < 4; ++mt) {
        int m = wm * 64 + mt * 16 + lo;
        af[mt] = *(const bf16x8*)(As + m * 128 + ((ks * 64 + lg * 16) ^ ((m & 7) << 4)));
      }
#pragma unroll
      for (int nt = 0; nt < 4; ++nt) {
        int n = wn * 64 + nt * 16 + lo;
        bf[nt] = *(const bf16x8*)(Bs + n * 128 + ((ks * 64 + lg * 16) ^ ((n & 7) << 4)));
      }
#pragma unroll
      for (int mt = 0; mt < 4; ++mt)
#pragma unroll
        for (int nt = 0; nt < 4; ++nt)
          acc[mt][nt] = MFMA16(af[mt], bf[nt], acc[mt][nt]);
    }
  }

  // ---- epilogue ----
  const int mat = nb >> 2;              // 0=q 1=k 2=v
  const int h = ((nb & 3) << 1) + wn;   // head of this wave's 64 cols
  const int win = mb * 2 + wm;          // window of this wave's 64 rows
  const size_t hb = ((size_t)win * 8 + h) * 4096;

  if (mat != 1) {
    const float* bsrc = (mat == 0) ? q_bias : v_bias;
    float bias[4];
#pragma unroll
    for (int nt = 0; nt < 4; ++nt) bias[nt] = bsrc[h * 64 + nt * 16 + lo];
#pragma unroll
    for (int mt = 0; mt < 4; ++mt)
#pragma unroll
      for (int nt = 0; nt < 4; ++nt)
#pragma unroll
        for (int r = 0; r < 4; ++r) acc[mt][nt][r] += bias[nt];
  }

  if (mat < 2) {
    bf16* dst = (bf16*)(ws + (mat == 0 ? OFF_QHAT : OFF_KHAT)) + hb;
#pragma unroll
    for (int mt = 0; mt < 4; ++mt) {
#pragma unroll
      for (int r = 0; r < 4; ++r) {
        float ss = acc[mt][0][r] * acc[mt][0][r] + acc[mt][1][r] * acc[mt][1][r] +
                   acc[mt][2][r] * acc[mt][2][r] + acc[mt][3][r] * acc[mt][3][r];
#pragma unroll
        for (int s = 1; s < 16; s <<= 1) ss += __shfl_xor(ss, s, 64);
        float rinv = 1.0f / fmaxf(sqrtf(ss), 1e-12f);
        int tok = mt * 16 + lg * 4 + r;
#pragma unroll
        for (int nt = 0; nt < 4; ++nt)
          dst[tok * 64 + nt * 16 + lo] = (bf16)(acc[mt][nt][r] * rinv);
      }
    }
  } else {
    bf16* dst = (bf16*)(ws + OFF_VT) + hb;   // [d][tok]
#pragma unroll
    for (int mt = 0; mt < 4; ++mt) {
#pragma unroll
      for (int nt = 0; nt < 4; ++nt) {
        ushort4 o;
        o.x = f2bf_bits(acc[mt][nt][0]); o.y = f2bf_bits(acc[mt][nt][1]);
        o.z = f2bf_bits(acc[mt][nt][2]); o.w = f2bf_bits(acc[mt][nt][3]);
        int d = nt * 16 + lo, tok0 = mt * 16 + lg * 4;
        *(ushort4*)(dst + d * 64 + tok0) = o;
      }
    }
  }
}

// ---------------------------------------------------------------------------
// K3: attention. 1024 blocks x 4 waves; wave w handles heads 2w, 2w+1.
// No block barriers; per-wave swizzled LDS for P, then reused for O bounce.
// ---------------------------------------------------------------------------
__launch_bounds__(256)
__global__ void attn_kernel(const float* __restrict__ logit_scale,
                            char* __restrict__ ws) {
  __shared__ __align__(16) char psb[4][8192];
  const int tid = threadIdx.x;
  const int w = tid >> 6, l = tid & 63, lg = l >> 4, lo = l & 15;
  const int b = blockIdx.x;
  const int widx = b & 63;
  char* pw = psb[w];
  const float* bmbase = (const float*)(ws + OFF_BM) + (size_t)widx * 8 * 4096;

#pragma unroll
  for (int hh = 0; hh < 2; ++hh) {
    const int h = w * 2 + hh;
    const size_t hb = ((size_t)b * 8 + h) * 4096;
    const bf16* qh = (const bf16*)(ws + OFF_QHAT) + hb;
    const bf16* kh = (const bf16*)(ws + OFF_KHAT) + hb;
    const bf16* vh = (const bf16*)(ws + OFF_VT) + hb;
    const float* bmp = bmbase + h * 4096;
    const float scale = __expf(fminf(logit_scale[h], 4.605170185988091f));

    // S = qhat @ khat^T
    f32x4 sacc[4][4];
#pragma unroll
    for (int mt = 0; mt < 4; ++mt)
#pragma unroll
      for (int nt = 0; nt < 4; ++nt) { f32x4 z = {0.f, 0.f, 0.f, 0.f}; sacc[mt][nt] = z; }
#pragma unroll
    for (int ks = 0; ks < 2; ++ks) {
      bf16x8 a4[4], b4[4];
#pragma unroll
      for (int mt = 0; mt < 4; ++mt)
        a4[mt] = *(const bf16x8*)(qh + (mt * 16 + lo) * 64 + ks * 32 + lg * 8);
#pragma unroll
      for (int nt = 0; nt < 4; ++nt)
        b4[nt] = *(const bf16x8*)(kh + (nt * 16 + lo) * 64 + ks * 32 + lg * 8);
#pragma unroll
      for (int mt = 0; mt < 4; ++mt)
#pragma unroll
        for (int nt = 0; nt < 4; ++nt)
          sacc[mt][nt] = MFMA16(a4[mt], b4[nt], sacc[mt][nt]);
    }

    // softmax (fp32, bm-table) + write P bf16 to swizzled per-wave LDS
    float invl[4][4];
#pragma unroll
    for (int mt = 0; mt < 4; ++mt) {
#pragma unroll
      for (int r = 0; r < 4; ++r) {
        int row = mt * 16 + lg * 4 + r;
        float sv[4];
#pragma unroll
        for (int nt = 0; nt < 4; ++nt)
          sv[nt] = fmaf(sacc[mt][nt][r], scale, bmp[row * 64 + nt * 16 + lo]);
        float mr = fmaxf(fmaxf(sv[0], sv[1]), fmaxf(sv[2], sv[3]));
#pragma unroll
        for (int s = 1; s < 16; s <<= 1) mr = fmaxf(mr, __shfl_xor(mr, s, 64));
        float ls = 0.f;
#pragma unroll
        for (int nt = 0; nt < 4; ++nt) { sv[nt] = __expf(sv[nt] - mr); ls += sv[nt]; }
#pragma unroll
        for (int s = 1; s < 16; s <<= 1) ls += __shfl_xor(ls, s, 64);
        invl[mt][r] = 1.0f / ls;
#pragma unroll
        for (int nt = 0; nt < 4; ++nt)
          *(bf16*)(pw + row * 128 + (((nt * 16 + lo) * 2) ^ ((row & 7) << 4))) = (bf16)sv[nt];
      }
    }
    asm volatile("" ::: "memory");   // P writes before P reads at IR level

    // O = P @ V  (B-operand = vT rows)
    f32x4 oacc[4][4];
#pragma unroll
    for (int mt = 0; mt < 4; ++mt)
#pragma unroll
      for (int nt = 0; nt < 4; ++nt) { f32x4 z = {0.f, 0.f, 0.f, 0.f}; oacc[mt][nt] = z; }
#pragma unroll
    for (int ks = 0; ks < 2; ++ks) {
      bf16x8 pa[4], b4[4];
#pragma unroll
      for (int mt = 0; mt < 4; ++mt) {
        int m = mt * 16 + lo;
        pa[mt] = *(const bf16x8*)(pw + m * 128 + ((ks * 64 + lg * 16) ^ ((m & 7) << 4)));
      }
#pragma unroll
      for (int nt = 0; nt < 4; ++nt)
        b4[nt] = *(const bf16x8*)(vh + (nt * 16 + lo) * 64 + ks * 32 + lg * 8);
#pragma unroll
      for (int mt = 0; mt < 4; ++mt)
#pragma unroll
        for (int nt = 0; nt < 4; ++nt)
          oacc[mt][nt] = MFMA16(pa[mt], b4[nt], oacc[mt][nt]);
    }
    asm volatile("" ::: "memory");   // P reads before O overwrites (per-wave DS in-order)

    // O -> LDS (tile-swizzled) -> coalesced 16B stores to pre-swizzled tile
#pragma unroll
    for (int mt = 0; mt < 4; ++mt) {
#pragma unroll
      for (int r = 0; r < 4; ++r) {
        int trow = mt * 16 + lg * 4 + r;
#pragma unroll
        for (int nt = 0; nt < 4; ++nt) {
          int d = nt * 16 + lo;
          *(bf16*)(pw + trow * 128 + ((d * 2) ^ ((trow & 7) << 4))) =
              (bf16)(oacc[mt][nt][r] * invl[mt][r]);
        }
      }
    }
    asm volatile("" ::: "memory");
    char* at2 = ws + OFF_ATTN + ((size_t)((b >> 1) * 8 + h) << 14) + (size_t)(b & 1) * 8192;
#pragma unroll
    for (int i = 0; i < 8; ++i) {
      int off = i * 1024 + l * 16;
      *(uint4*)(at2 + off) = *(const uint4*)(pw + off);
    }
    asm volatile("" ::: "memory");   // O copy before next head reuses pw
  }
}

// ---------------------------------------------------------------------------
// K4: proj GEMM. out = attn(bf16 tiles) @ proj_w^T(bf16 tiles) + proj_b.
// Both operands via global_load_lds (pre-swizzled), conflict-free ds_read.
// ---------------------------------------------------------------------------
__launch_bounds__(256)
__global__ void proj_kernel(const float* __restrict__ proj_b,
                            float* __restrict__ out,
                            const char* __restrict__ ws) {
  __shared__ __align__(16) char As[16384];
  __shared__ __align__(16) char Bs[16384];
  const int tid = threadIdx.x;
  const int w = tid >> 6, l = tid & 63, lg = l >> 4, lo = l & 15;
  const int wm = w >> 1, wn = w & 1;
  const int bid = blockIdx.x;
  const int wg = (bid & 7) * 256 + (bid >> 3);   // 2048 % 8 == 0
  const int mb = wg >> 2, nbp = wg & 3;

  const char* at_base = ws + OFF_ATTN + ((size_t)mb * 8 << 14);
  const char* bt_base = ws + OFF_PROJWT + (unsigned)(nbp * 8 << 14);

  f32x4 acc[4][4];
#pragma unroll
  for (int mt = 0; mt < 4; ++mt)
#pragma unroll
    for (int nt = 0; nt < 4; ++nt) { f32x4 z = {0.f, 0.f, 0.f, 0.f}; acc[mt][nt] = z; }

#pragma unroll 1
  for (int kc = 0; kc < 8; ++kc) {
    __syncthreads();
    const char* at = at_base + (kc << 14);
    const char* bt = bt_base + (kc << 14);
#pragma unroll
    for (int i = 0; i < 4; ++i) {
      int chunk = i * 4 + w;
      gload_lds16(at + chunk * 1024 + l * 16, As + chunk * 1024);
      gload_lds16(bt + chunk * 1024 + l * 16, Bs + chunk * 1024);
    }
    __syncthreads();
#pragma unroll
    for (int ks = 0; ks < 2; ++ks) {
      bf16x8 af[4], bf[4];
#pragma unroll
      for (int mt = 0; mt < 4; ++mt) {
        int m = wm * 64 + mt * 16 + lo;
        af[mt] = *(const bf16x8*)(As + m * 128 + ((ks * 64 + lg * 16) ^ ((m & 7) << 4)));
      }
#pragma unroll
      for (int nt = 0; nt < 4; ++nt) {
        int n = wn * 64 + nt * 16 + lo;
        bf[nt] = *(const bf16x8*)(Bs + n * 128 + ((ks * 64 + lg * 16) ^ ((n & 7) << 4)));
      }
#pragma unroll
      for (int mt = 0; mt < 4; ++mt)
#pragma unroll
        for (int nt = 0; nt < 4; ++nt)
          acc[mt][nt] = MFMA16(af[mt], bf[nt], acc[mt][nt]);
    }
  }
#pragma unroll
  for (int nt = 0; nt < 4; ++nt) {
    int col = nbp * 128 + wn * 64 + nt * 16 + lo;
    float pb = proj_b[col];
#pragma unroll
    for (int mt = 0; mt < 4; ++mt) {
#pragma unroll
      for (int r = 0; r < 4; ++r) {
        int row = mb * 128 + wm * 64 + mt * 16 + lg * 4 + r;
        out[(size_t)row * 512 + col] = acc[mt][nt][r] + pb;
      }
    }
  }
}

// ---------------------------------------------------------------------------
extern "C" void kernel_launch(void* const* d_in, const int* in_sizes, int n_in,
                              void* d_out, int out_size, void* d_ws, size_t ws_size,
                              hipStream_t stream) {
  const float* x      = (const float*)d_in[0];
  const float* mask   = (const float*)d_in[1];
  const float* qkvw   = (const float*)d_in[2];
  const float* q_bias = (const float*)d_in[3];
  const float* v_bias = (const float*)d_in[4];
  const float* ls     = (const float*)d_in[5];
  const float* cpb_w1 = (const float*)d_in[6];
  const float* cpb_b1 = (const float*)d_in[7];
  const float* cpb_w2 = (const float*)d_in[8];
  const float* proj_w = (const float*)d_in[9];
  const float* proj_b = (const float*)d_in[10];
  float* out = (float*)d_out;
  char* ws = (char*)d_ws;

  hipLaunchKernelGGL(wconv_kernel, dim3(256), dim3(256), 0, stream, qkvw, proj_w, ws);
  hipLaunchKernelGGL(xconv_kernel, dim3(8192), dim3(256), 0, stream, x, ws);
  hipLaunchKernelGGL(cpb_kernel, dim3(225), dim3(256), 0, stream,
                     cpb_w1, cpb_b1, cpb_w2, (float*)(ws + OFF_CPB));
  hipLaunchKernelGGL(bmask_kernel, dim3(512), dim3(256), 0, stream,
                     mask, (const float*)(ws + OFF_CPB), (float*)(ws + OFF_BM));
  hipLaunchKernelGGL(qkv_gemm, dim3(6144), dim3(256), 0, stream, q_bias, v_bias, ws);
  hipLaunchKernelGGL(attn_kernel, dim3(1024), dim3(256), 0, stream, ls, ws);
  hipLaunchKernelGGL(proj_kernel, dim3(2048), dim3(256), 0, stream, proj_b, out, ws);
}